// Round 2
// baseline (475.108 us; speedup 1.0000x reference)
//
#include <hip/hip_runtime.h>
#include <cmath>
#include <cstdint>

#define S_LEN 4096
#define NH 16
#define HD 64

typedef __attribute__((ext_vector_type(8))) short bf16x8;
typedef __attribute__((ext_vector_type(4))) float f32x4;
typedef __attribute__((ext_vector_type(4))) unsigned short u16x4;
typedef __attribute__((ext_vector_type(4))) unsigned int u32x4;
typedef __attribute__((ext_vector_type(4))) float f4;

__device__ __forceinline__ unsigned short f2bf(float f) {
  union { float f; unsigned u; } v; v.f = f;
  unsigned u = v.u;
  u += 0x7FFFu + ((u >> 16) & 1u);
  return (unsigned short)(u >> 16);
}
__device__ __forceinline__ float bf2f(unsigned short h) {
  union { unsigned u; float f; } v; v.u = ((unsigned)h) << 16;
  return v.f;
}
__device__ __forceinline__ void split2(float x, unsigned short& h, unsigned short& l) {
  h = f2bf(x);
  l = f2bf(x - bf2f(h));
}
__device__ __forceinline__ void unpack8(const unsigned* p, bf16x8& hi, bf16x8& lo) {
  u32x4 a = *(const u32x4*)p;
  u32x4 b = *(const u32x4*)(p + 4);
#pragma unroll
  for (int i = 0; i < 4; i++) {
    hi[i]     = (short)(a[i] & 0xFFFFu);
    lo[i]     = (short)(a[i] >> 16);
    hi[4 + i] = (short)(b[i] & 0xFFFFu);
    lo[4 + i] = (short)(b[i] >> 16);
  }
}

#define GLL16(g, l) __builtin_amdgcn_global_load_lds( \
    (const __attribute__((address_space(1))) void*)(g), \
    (__attribute__((address_space(3))) void*)(l), 16, 0, 0)

// ---------------------------------------------------------------- convert
// hs, Wq, Wk -> hi/lo split pairs; Wv, Wo -> plain bf16.
__global__ __launch_bounds__(256) void cvt_kernel(
    const float* __restrict__ hs, const float* __restrict__ wq,
    const float* __restrict__ wk, const float* __restrict__ wv,
    const float* __restrict__ wo,
    unsigned short* __restrict__ hsh, unsigned short* __restrict__ hsl,
    unsigned short* __restrict__ wqh, unsigned short* __restrict__ wql,
    unsigned short* __restrict__ wkh, unsigned short* __restrict__ wkl,
    unsigned short* __restrict__ wvb, unsigned short* __restrict__ wob)
{
  const int HID4 = (S_LEN * 1024) / 4;   // 1048576
  const int W4   = (1024 * 1024) / 4;    // 262144
  const int total = HID4 + 4 * W4;
  for (int i = blockIdx.x * 256 + threadIdx.x; i < total;
       i += gridDim.x * 256) {
    const float* s; unsigned short *dh, *dl; int off;
    if (i < HID4) { s = hs; dh = hsh; dl = hsl; off = i; }
    else {
      int j = i - HID4; int w = j >> 18; off = j & (W4 - 1);
      if (w == 0)      { s = wq; dh = wqh; dl = wql; }
      else if (w == 1) { s = wk; dh = wkh; dl = wkl; }
      else if (w == 2) { s = wv; dh = wvb; dl = nullptr; }
      else             { s = wo; dh = wob; dl = nullptr; }
    }
    f4 v = *(const f4*)(s + (size_t)off * 4);
    u16x4 rh, rl;
#pragma unroll
    for (int j = 0; j < 4; j++) {
      unsigned short h, l; split2(v[j], h, l);
      rh[j] = h; rl[j] = l;
    }
    *(u16x4*)(dh + (size_t)off * 4) = rh;
    if (dl) *(u16x4*)(dl + (size_t)off * 4) = rl;
  }
}

// ---------------------------------------------------------------- rope table
__global__ __launch_bounds__(256) void rope_table(
    float* __restrict__ cosT, float* __restrict__ sinT, double base)
{
  int idx = blockIdx.x * 256 + threadIdx.x;
  if (idx >= S_LEN * 32) return;
  int t = idx >> 5, j = idx & 31;
  double invf = pow(base, -(double)j / 32.0);
  double f = fmod((double)t * invf, 6.283185307179586476925286766559);
  float ff = (float)f;
  cosT[idx] = cosf(ff);
  sinT[idx] = sinf(ff);
}

// ---------------------------------------------------------------- split GEMM (NT)
// C = (Ah+Al)*(Bh+Bl)^T ~= Ah*Bh + Ah*Bl + Al*Bh; fp32 out to [head][s][d].
// z selects (Bh0,Bl0,O0) or (Bh1,Bl1,O1).
__global__ __launch_bounds__(256) void gemm_split(
    const unsigned short* __restrict__ Ah, const unsigned short* __restrict__ Al,
    const unsigned short* __restrict__ Bh0, const unsigned short* __restrict__ Bl0,
    const unsigned short* __restrict__ Bh1, const unsigned short* __restrict__ Bl1,
    float* O0, float* O1, int M, int K)
{
  __shared__ unsigned short Ash[128 * 64];
  __shared__ unsigned short Asl[128 * 64];
  __shared__ unsigned short Bsh[128 * 64];
  __shared__ unsigned short Bsl[128 * 64];
  const unsigned short* Bh = blockIdx.z ? Bh1 : Bh0;
  const unsigned short* Bl = blockIdx.z ? Bl1 : Bl0;
  float* O = blockIdx.z ? O1 : O0;
  const int m0 = blockIdx.y * 128, n0 = blockIdx.x * 128;
  const int tid = threadIdx.x, wid = tid >> 6, lane = tid & 63;
  const int lr = lane & 15, lk = (lane >> 4) * 8;
  const int wr = (wid >> 1) * 64, wc = (wid & 1) * 64;
  const int strow = lane >> 3;
  const int stcol = (lane & 7) * 8;

  f32x4 acc[4][4];
#pragma unroll
  for (int m = 0; m < 4; m++)
#pragma unroll
    for (int n = 0; n < 4; n++) acc[m][n] = (f32x4){0.f, 0.f, 0.f, 0.f};

  for (int kt = 0; kt < K; kt += 64) {
#pragma unroll
    for (int i = 0; i < 4; i++) {
      int c = wid * 4 + i;
      int row = c * 8 + strow;
      GLL16(Ah + (size_t)(m0 + row) * K + kt + stcol, &Ash[c * 512]);
      GLL16(Al + (size_t)(m0 + row) * K + kt + stcol, &Asl[c * 512]);
      GLL16(Bh + (size_t)(n0 + row) * K + kt + stcol, &Bsh[c * 512]);
      GLL16(Bl + (size_t)(n0 + row) * K + kt + stcol, &Bsl[c * 512]);
    }
    __syncthreads();
    bf16x8 ah[4][2], al[4][2], bh[4][2], bl[4][2];
#pragma unroll
    for (int m = 0; m < 4; m++)
#pragma unroll
      for (int kk = 0; kk < 2; kk++) {
        ah[m][kk] = *(const bf16x8*)&Ash[(wr + m * 16 + lr) * 64 + kk * 32 + lk];
        al[m][kk] = *(const bf16x8*)&Asl[(wr + m * 16 + lr) * 64 + kk * 32 + lk];
      }
#pragma unroll
    for (int n = 0; n < 4; n++)
#pragma unroll
      for (int kk = 0; kk < 2; kk++) {
        bh[n][kk] = *(const bf16x8*)&Bsh[(wc + n * 16 + lr) * 64 + kk * 32 + lk];
        bl[n][kk] = *(const bf16x8*)&Bsl[(wc + n * 16 + lr) * 64 + kk * 32 + lk];
      }
#pragma unroll
    for (int m = 0; m < 4; m++)
#pragma unroll
      for (int n = 0; n < 4; n++)
#pragma unroll
        for (int kk = 0; kk < 2; kk++) {
          acc[m][n] = __builtin_amdgcn_mfma_f32_16x16x32_bf16(
              al[m][kk], bh[n][kk], acc[m][n], 0, 0, 0);
          acc[m][n] = __builtin_amdgcn_mfma_f32_16x16x32_bf16(
              ah[m][kk], bl[n][kk], acc[m][n], 0, 0, 0);
          acc[m][n] = __builtin_amdgcn_mfma_f32_16x16x32_bf16(
              ah[m][kk], bh[n][kk], acc[m][n], 0, 0, 0);
        }
    __syncthreads();
  }

  const int rbase = m0 + wr + (lane >> 4) * 4;
  const int cbase = n0 + wc + lr;
#pragma unroll
  for (int m = 0; m < 4; m++)
#pragma unroll
    for (int n = 0; n < 4; n++)
#pragma unroll
      for (int j = 0; j < 4; j++) {
        int s = rbase + m * 16 + j;
        int o = cbase + n * 16;
        O[((size_t)(o >> 6) * M + s) * HD + (o & 63)] = acc[m][n][j];
      }
}

// ---------------------------------------------------------------- plain GEMM (NT)
// mode 1: bf16 out to [head][s][d];  mode 2: fp32 out row-major [M][N]
__global__ __launch_bounds__(256) void gemm_nt(
    const unsigned short* __restrict__ A,
    const unsigned short* __restrict__ B0,
    void* O0, int M, int N, int K, int mode)
{
  __shared__ unsigned short As[128 * 64];
  __shared__ unsigned short Bs[128 * 64];
  const unsigned short* B = B0;
  void* O = O0;
  const int m0 = blockIdx.y * 128, n0 = blockIdx.x * 128;
  const int tid = threadIdx.x, wid = tid >> 6, lane = tid & 63;
  const int lr = lane & 15, lk = (lane >> 4) * 8;
  const int wr = (wid >> 1) * 64, wc = (wid & 1) * 64;
  const int strow = lane >> 3;
  const int stcol = (lane & 7) * 8;

  f32x4 acc[4][4];
#pragma unroll
  for (int m = 0; m < 4; m++)
#pragma unroll
    for (int n = 0; n < 4; n++) acc[m][n] = (f32x4){0.f, 0.f, 0.f, 0.f};

  for (int kt = 0; kt < K; kt += 64) {
#pragma unroll
    for (int i = 0; i < 4; i++) {
      int c = wid * 4 + i;
      int row = c * 8 + strow;
      GLL16(A + (size_t)(m0 + row) * K + kt + stcol, &As[c * 512]);
      GLL16(B + (size_t)(n0 + row) * K + kt + stcol, &Bs[c * 512]);
    }
    __syncthreads();
    bf16x8 af[4][2], bfr[4][2];
#pragma unroll
    for (int m = 0; m < 4; m++)
#pragma unroll
      for (int kk = 0; kk < 2; kk++)
        af[m][kk] = *(const bf16x8*)&As[(wr + m * 16 + lr) * 64 + kk * 32 + lk];
#pragma unroll
    for (int n = 0; n < 4; n++)
#pragma unroll
      for (int kk = 0; kk < 2; kk++)
        bfr[n][kk] = *(const bf16x8*)&Bs[(wc + n * 16 + lr) * 64 + kk * 32 + lk];
#pragma unroll
    for (int m = 0; m < 4; m++)
#pragma unroll
      for (int n = 0; n < 4; n++)
#pragma unroll
        for (int kk = 0; kk < 2; kk++)
          acc[m][n] = __builtin_amdgcn_mfma_f32_16x16x32_bf16(
              af[m][kk], bfr[n][kk], acc[m][n], 0, 0, 0);
    __syncthreads();
  }

  const int rbase = m0 + wr + (lane >> 4) * 4;
  const int cbase = n0 + wc + lr;
  if (mode == 1) {
    unsigned short* Q = (unsigned short*)O;
#pragma unroll
    for (int m = 0; m < 4; m++)
#pragma unroll
      for (int n = 0; n < 4; n++)
#pragma unroll
        for (int j = 0; j < 4; j++) {
          int s = rbase + m * 16 + j;
          int o = cbase + n * 16;
          Q[((size_t)(o >> 6) * M + s) * HD + (o & 63)] = f2bf(acc[m][n][j]);
        }
  } else {
    float* C = (float*)O;
#pragma unroll
    for (int m = 0; m < 4; m++)
#pragma unroll
      for (int n = 0; n < 4; n++)
#pragma unroll
        for (int j = 0; j < 4; j++) {
          int s = rbase + m * 16 + j;
          int o = cbase + n * 16;
          C[(size_t)s * N + o] = acc[m][n][j];
        }
  }
}

// ---------------------------------------------------------------- rope apply
// Q,K fp32 [head][s][d]; rotate in fp32; write packed u32 (hi | lo<<16) in place.
__global__ __launch_bounds__(256) void rope_apply(
    float* __restrict__ Qf, float* __restrict__ Kf,
    const float* __restrict__ cosT, const float* __restrict__ sinT)
{
  int wid = threadIdx.x >> 6, lane = threadIdx.x & 63;
  int row = blockIdx.x * 4 + wid;
  int t = row & (S_LEN - 1);
  int j = (lane < 32) ? lane : (lane - 32);
  float c = cosT[t * 32 + j], s = sinT[t * 32 + j];
  int partner = (lane < 32) ? (2 * lane + 1) : (2 * (lane - 32));
  float sgn = (lane < 32) ? -1.0f : 1.0f;
  float* qp = Qf + (size_t)row * HD;
  float* kp = Kf + (size_t)row * HD;
  float q = qp[lane], k = kp[lane];
  float qo = __shfl(q, partner, 64);
  float ko = __shfl(k, partner, 64);
  float qr = q * c + sgn * qo * s;
  float kr = k * c + sgn * ko * s;
  unsigned short qh, ql, kh, kl;
  split2(qr, qh, ql); split2(kr, kh, kl);
  ((unsigned*)qp)[lane] = (unsigned)qh | ((unsigned)ql << 16);
  ((unsigned*)kp)[lane] = (unsigned)kh | ((unsigned)kl << 16);
}

// ---------------------------------------------------------------- attention
// Q,K packed u32 (hi|lo<<16) [head][s][d]; V bf16 [head][s][d].
// grid (S_LEN/64, NH), 4 waves/block, 16 q rows per wave. scores = (q.k)*8.
__global__ __launch_bounds__(256) void attn_kernel(
    const unsigned* __restrict__ Q, const unsigned* __restrict__ K,
    const unsigned short* __restrict__ V, unsigned short* __restrict__ Oattn)
{
  __shared__ unsigned short Ksh[64 * 72];
  __shared__ unsigned short Ksl[64 * 72];
  __shared__ unsigned VT32[64 * 36];
  __shared__ unsigned short Ps[4][16 * 72];

  const int h = blockIdx.y;
  const int tid = threadIdx.x, wid = tid >> 6, lane = tid & 63;
  const int lr = lane & 15, lk = (lane >> 4) * 8;
  const int qw = blockIdx.x * 64 + wid * 16;
  const unsigned* Kh = K + (size_t)h * S_LEN * HD;
  const unsigned short* Vh = V + (size_t)h * S_LEN * HD;
  unsigned short* Vsh = (unsigned short*)VT32;

  // Q fragments hi/lo
  const unsigned* Qrow = Q + ((size_t)h * S_LEN + qw + lr) * HD;
  bf16x8 qh[2], ql[2];
  unpack8(&Qrow[lk], qh[0], ql[0]);
  unpack8(&Qrow[32 + lk], qh[1], ql[1]);

  f32x4 acc_o[4];
#pragma unroll
  for (int nb = 0; nb < 4; nb++) acc_o[nb] = (f32x4){0.f, 0.f, 0.f, 0.f};
  float m_r[4], l_r[4];
#pragma unroll
  for (int r = 0; r < 4; r++) { m_r[r] = -__builtin_inff(); l_r[r] = 0.f; }

  for (int kv = 0; kv < S_LEN; kv += 64) {
    // ---- stage K hi/lo (row-major, padded) ----
#pragma unroll
    for (int rep = 0; rep < 2; rep++) {
      int c = tid + rep * 256;
      int row = c >> 3, col8 = (c & 7) * 8;
      bf16x8 hi, lo;
      unpack8(&Kh[(size_t)(kv + row) * HD + col8], hi, lo);
      *(bf16x8*)&Ksh[row * 72 + col8] = hi;
      *(bf16x8*)&Ksl[row * 72 + col8] = lo;
    }
    // ---- stage V transposed (u32 key-pairs) ----
    {
      int cc = tid & 7, k2 = tid >> 3;
      bf16x8 va = *(const bf16x8*)&Vh[(size_t)(kv + 2 * k2) * HD + cc * 8];
      bf16x8 vb = *(const bf16x8*)&Vh[(size_t)(kv + 2 * k2 + 1) * HD + cc * 8];
#pragma unroll
      for (int i = 0; i < 8; i++) {
        unsigned lo = (unsigned)(unsigned short)va[i];
        unsigned hi = (unsigned)(unsigned short)vb[i];
        VT32[(cc * 8 + i) * 36 + k2] = lo | (hi << 16);
      }
    }
    __syncthreads();

    // ---- S = Q K^T (3-term split) ----
    f32x4 accs[4];
#pragma unroll
    for (int jb = 0; jb < 4; jb++) accs[jb] = (f32x4){0.f, 0.f, 0.f, 0.f};
#pragma unroll
    for (int jb = 0; jb < 4; jb++)
#pragma unroll
      for (int ks = 0; ks < 2; ks++) {
        bf16x8 kh = *(const bf16x8*)&Ksh[(jb * 16 + lr) * 72 + ks * 32 + lk];
        bf16x8 kl = *(const bf16x8*)&Ksl[(jb * 16 + lr) * 72 + ks * 32 + lk];
        accs[jb] = __builtin_amdgcn_mfma_f32_16x16x32_bf16(ql[ks], kh, accs[jb], 0, 0, 0);
        accs[jb] = __builtin_amdgcn_mfma_f32_16x16x32_bf16(qh[ks], kl, accs[jb], 0, 0, 0);
        accs[jb] = __builtin_amdgcn_mfma_f32_16x16x32_bf16(qh[ks], kh, accs[jb], 0, 0, 0);
      }

    // ---- online softmax (row = (lane>>4)*4 + r, col = lane&15) ----
    float sc[4][4];
#pragma unroll
    for (int jb = 0; jb < 4; jb++)
#pragma unroll
      for (int r = 0; r < 4; r++) sc[jb][r] = accs[jb][r] * 8.0f;

    float alpha[4];
#pragma unroll
    for (int r = 0; r < 4; r++) {
      float mx = fmaxf(fmaxf(sc[0][r], sc[1][r]), fmaxf(sc[2][r], sc[3][r]));
      mx = fmaxf(mx, __shfl_xor(mx, 1));
      mx = fmaxf(mx, __shfl_xor(mx, 2));
      mx = fmaxf(mx, __shfl_xor(mx, 4));
      mx = fmaxf(mx, __shfl_xor(mx, 8));
      float mnew = fmaxf(m_r[r], mx);
      alpha[r] = __expf(m_r[r] - mnew);
      m_r[r] = mnew;
    }
    float rs[4] = {0.f, 0.f, 0.f, 0.f};
#pragma unroll
    for (int jb = 0; jb < 4; jb++)
#pragma unroll
      for (int r = 0; r < 4; r++) {
        float p = __expf(sc[jb][r] - m_r[r]);
        rs[r] += p;
        Ps[wid][((lane >> 4) * 4 + r) * 72 + jb * 16 + lr] = f2bf(p);
      }
#pragma unroll
    for (int r = 0; r < 4; r++) {
      float t = rs[r];
      t += __shfl_xor(t, 1);
      t += __shfl_xor(t, 2);
      t += __shfl_xor(t, 4);
      t += __shfl_xor(t, 8);
      l_r[r] = l_r[r] * alpha[r] + t;
    }
#pragma unroll
    for (int nb = 0; nb < 4; nb++)
#pragma unroll
      for (int r = 0; r < 4; r++) acc_o[nb][r] *= alpha[r];

    // ---- O += P V ----
#pragma unroll
    for (int ks = 0; ks < 2; ks++) {
      bf16x8 pa = *(const bf16x8*)&Ps[wid][lr * 72 + ks * 32 + lk];
#pragma unroll
      for (int nb = 0; nb < 4; nb++) {
        bf16x8 bv = *(const bf16x8*)&Vsh[(nb * 16 + lr) * 72 + ks * 32 + lk];
        acc_o[nb] = __builtin_amdgcn_mfma_f32_16x16x32_bf16(pa, bv, acc_o[nb], 0, 0, 0);
      }
    }
    __syncthreads();
  }

  // ---- epilogue ----
#pragma unroll
  for (int nb = 0; nb < 4; nb++)
#pragma unroll
    for (int r = 0; r < 4; r++) {
      float v = acc_o[nb][r] / l_r[r];
      int s = qw + (lane >> 4) * 4 + r;
      int col = h * HD + nb * 16 + lr;
      Oattn[(size_t)s * 1024 + col] = f2bf(v);
    }
}

// ---------------------------------------------------------------- launch
extern "C" void kernel_launch(void* const* d_in, const int* in_sizes, int n_in,
                              void* d_out, int out_size, void* d_ws, size_t ws_size,
                              hipStream_t stream)
{
  const float* hs = (const float*)d_in[0];
  const float* Wq = (const float*)d_in[1];
  const float* Wk = (const float*)d_in[2];
  const float* Wv = (const float*)d_in[3];
  const float* Wo = (const float*)d_in[4];

  char* ws = (char*)d_ws;
  const size_t HS = (size_t)S_LEN * 1024;      // 4194304 elems
  const size_t WN = (size_t)1024 * 1024;       // 1048576 elems
  size_t off = 0;
  unsigned short* hsh = (unsigned short*)(ws + off); off += HS * 2;   // 8.39MB
  unsigned short* hsl = (unsigned short*)(ws + off); off += HS * 2;
  unsigned short* wqh = (unsigned short*)(ws + off); off += WN * 2;
  unsigned short* wql = (unsigned short*)(ws + off); off += WN * 2;
  unsigned short* wkh = (unsigned short*)(ws + off); off += WN * 2;
  unsigned short* wkl = (unsigned short*)(ws + off); off += WN * 2;
  unsigned short* wvb = (unsigned short*)(ws + off); off += WN * 2;
  unsigned short* wob = (unsigned short*)(ws + off); off += WN * 2;
  float* Qf = (float*)(ws + off); off += HS * 4;                      // 16.78MB
  float* Kf = (float*)(ws + off); off += HS * 4;
  unsigned short* Vb = (unsigned short*)(ws + off); off += HS * 2;
  float* cosT = (float*)(ws + off); off += (size_t)S_LEN * 32 * 4;
  float* sinT = (float*)(ws + off); off += (size_t)S_LEN * 32 * 4;
  unsigned short* Ab = hsh;  // reuse: hs splits dead after projections

  cvt_kernel<<<4096, 256, 0, stream>>>(hs, Wq, Wk, Wv, Wo,
                                       hsh, hsl, wqh, wql, wkh, wkl, wvb, wob);

  double base = 10000.0 * pow((double)S_LEN / 2048.0, 64.0 / 62.0);
  rope_table<<<(S_LEN * 32 + 255) / 256, 256, 0, stream>>>(cosT, sinT, base);

  gemm_split<<<dim3(8, 32, 2), 256, 0, stream>>>(
      hsh, hsl, wqh, wql, wkh, wkl, Qf, Kf, S_LEN, 1024);

  gemm_nt<<<dim3(8, 32, 1), 256, 0, stream>>>(
      hsh, wvb, Vb, S_LEN, 1024, 1024, 1);

  rope_apply<<<NH * S_LEN / 4, 256, 0, stream>>>(Qf, Kf, cosT, sinT);

  attn_kernel<<<dim3(S_LEN / 64, NH), 256, 0, stream>>>(
      (const unsigned*)Qf, (const unsigned*)Kf, Vb, Ab);

  gemm_nt<<<dim3(8, 32, 1), 256, 0, stream>>>(
      Ab, wob, d_out, S_LEN, 1024, 1024, 2);
}

// Round 3
// 404.905 us; speedup vs baseline: 1.1734x; 1.1734x over previous
//
#include <hip/hip_runtime.h>
#include <cmath>
#include <cstdint>

#define S_LEN 4096
#define NH 16
#define HD 64

typedef __attribute__((ext_vector_type(8))) short bf16x8;
typedef __attribute__((ext_vector_type(4))) float f32x4;
typedef __attribute__((ext_vector_type(4))) unsigned short u16x4;
typedef __attribute__((ext_vector_type(4))) unsigned int u32x4;
typedef __attribute__((ext_vector_type(4))) float f4;

__device__ __forceinline__ unsigned short f2bf(float f) {
  union { float f; unsigned u; } v; v.f = f;
  unsigned u = v.u;
  u += 0x7FFFu + ((u >> 16) & 1u);
  return (unsigned short)(u >> 16);
}
__device__ __forceinline__ float bf2f(unsigned short h) {
  union { unsigned u; float f; } v; v.u = ((unsigned)h) << 16;
  return v.f;
}
__device__ __forceinline__ void split2(float x, unsigned short& h, unsigned short& l) {
  h = f2bf(x);
  l = f2bf(x - bf2f(h));
}
__device__ __forceinline__ void unpack8(const unsigned* p, bf16x8& hi, bf16x8& lo) {
  u32x4 a = *(const u32x4*)p;
  u32x4 b = *(const u32x4*)(p + 4);
#pragma unroll
  for (int i = 0; i < 4; i++) {
    hi[i]     = (short)(a[i] & 0xFFFFu);
    lo[i]     = (short)(a[i] >> 16);
    hi[4 + i] = (short)(b[i] & 0xFFFFu);
    lo[4 + i] = (short)(b[i] >> 16);
  }
}

#define GLL16(g, l) __builtin_amdgcn_global_load_lds( \
    (const __attribute__((address_space(1))) void*)(g), \
    (__attribute__((address_space(3))) void*)(l), 16, 0, 0)

// per-head byte size of a swizzled-tile plane: 4096 rows * 128B
#define PLANE_BYTES 524288
// one 64x64 bf16 tile: 8KB
#define TILE_BYTES 8192

// ---------------------------------------------------------------- convert
// hs, Wq, Wk -> hi/lo split pairs; Wv, Wo -> plain bf16.
__global__ __launch_bounds__(256) void cvt_kernel(
    const float* __restrict__ hs, const float* __restrict__ wq,
    const float* __restrict__ wk, const float* __restrict__ wv,
    const float* __restrict__ wo,
    unsigned short* __restrict__ hsh, unsigned short* __restrict__ hsl,
    unsigned short* __restrict__ wqh, unsigned short* __restrict__ wql,
    unsigned short* __restrict__ wkh, unsigned short* __restrict__ wkl,
    unsigned short* __restrict__ wvb, unsigned short* __restrict__ wob)
{
  const int HID4 = (S_LEN * 1024) / 4;   // 1048576
  const int W4   = (1024 * 1024) / 4;    // 262144
  const int total = HID4 + 4 * W4;
  for (int i = blockIdx.x * 256 + threadIdx.x; i < total;
       i += gridDim.x * 256) {
    const float* s; unsigned short *dh, *dl; int off;
    if (i < HID4) { s = hs; dh = hsh; dl = hsl; off = i; }
    else {
      int j = i - HID4; int w = j >> 18; off = j & (W4 - 1);
      if (w == 0)      { s = wq; dh = wqh; dl = wql; }
      else if (w == 1) { s = wk; dh = wkh; dl = wkl; }
      else if (w == 2) { s = wv; dh = wvb; dl = nullptr; }
      else             { s = wo; dh = wob; dl = nullptr; }
    }
    f4 v = *(const f4*)(s + (size_t)off * 4);
    u16x4 rh, rl;
#pragma unroll
    for (int j = 0; j < 4; j++) {
      unsigned short h, l; split2(v[j], h, l);
      rh[j] = h; rl[j] = l;
    }
    *(u16x4*)(dh + (size_t)off * 4) = rh;
    if (dl) *(u16x4*)(dl + (size_t)off * 4) = rl;
  }
}

// ---------------------------------------------------------------- rope table
__global__ __launch_bounds__(256) void rope_table(
    float* __restrict__ cosT, float* __restrict__ sinT, double base)
{
  int idx = blockIdx.x * 256 + threadIdx.x;
  if (idx >= S_LEN * 32) return;
  int t = idx >> 5, j = idx & 31;
  double invf = pow(base, -(double)j / 32.0);
  double f = fmod((double)t * invf, 6.283185307179586476925286766559);
  float ff = (float)f;
  cosT[idx] = cosf(ff);
  sinT[idx] = sinf(ff);
}

// ---------------------------------------------------------------- split GEMM (NT)
// C = (Ah+Al)*(Bh+Bl)^T ~= Ah*Bh + Ah*Bl + Al*Bh; fp32 out to [head][s][d].
__global__ __launch_bounds__(256) void gemm_split(
    const unsigned short* __restrict__ Ah, const unsigned short* __restrict__ Al,
    const unsigned short* __restrict__ Bh0, const unsigned short* __restrict__ Bl0,
    const unsigned short* __restrict__ Bh1, const unsigned short* __restrict__ Bl1,
    float* O0, float* O1, int M, int K)
{
  __shared__ unsigned short Ash[128 * 64];
  __shared__ unsigned short Asl[128 * 64];
  __shared__ unsigned short Bsh[128 * 64];
  __shared__ unsigned short Bsl[128 * 64];
  const unsigned short* Bh = blockIdx.z ? Bh1 : Bh0;
  const unsigned short* Bl = blockIdx.z ? Bl1 : Bl0;
  float* O = blockIdx.z ? O1 : O0;
  const int m0 = blockIdx.y * 128, n0 = blockIdx.x * 128;
  const int tid = threadIdx.x, wid = tid >> 6, lane = tid & 63;
  const int lr = lane & 15, lk = (lane >> 4) * 8;
  const int wr = (wid >> 1) * 64, wc = (wid & 1) * 64;
  const int strow = lane >> 3;
  const int stcol = (lane & 7) * 8;

  f32x4 acc[4][4];
#pragma unroll
  for (int m = 0; m < 4; m++)
#pragma unroll
    for (int n = 0; n < 4; n++) acc[m][n] = (f32x4){0.f, 0.f, 0.f, 0.f};

  for (int kt = 0; kt < K; kt += 64) {
#pragma unroll
    for (int i = 0; i < 4; i++) {
      int c = wid * 4 + i;
      int row = c * 8 + strow;
      GLL16(Ah + (size_t)(m0 + row) * K + kt + stcol, &Ash[c * 512]);
      GLL16(Al + (size_t)(m0 + row) * K + kt + stcol, &Asl[c * 512]);
      GLL16(Bh + (size_t)(n0 + row) * K + kt + stcol, &Bsh[c * 512]);
      GLL16(Bl + (size_t)(n0 + row) * K + kt + stcol, &Bsl[c * 512]);
    }
    __syncthreads();
    bf16x8 ah[4][2], al[4][2], bh[4][2], bl[4][2];
#pragma unroll
    for (int m = 0; m < 4; m++)
#pragma unroll
      for (int kk = 0; kk < 2; kk++) {
        ah[m][kk] = *(const bf16x8*)&Ash[(wr + m * 16 + lr) * 64 + kk * 32 + lk];
        al[m][kk] = *(const bf16x8*)&Asl[(wr + m * 16 + lr) * 64 + kk * 32 + lk];
      }
#pragma unroll
    for (int n = 0; n < 4; n++)
#pragma unroll
      for (int kk = 0; kk < 2; kk++) {
        bh[n][kk] = *(const bf16x8*)&Bsh[(wc + n * 16 + lr) * 64 + kk * 32 + lk];
        bl[n][kk] = *(const bf16x8*)&Bsl[(wc + n * 16 + lr) * 64 + kk * 32 + lk];
      }
#pragma unroll
    for (int m = 0; m < 4; m++)
#pragma unroll
      for (int n = 0; n < 4; n++)
#pragma unroll
        for (int kk = 0; kk < 2; kk++) {
          acc[m][n] = __builtin_amdgcn_mfma_f32_16x16x32_bf16(
              al[m][kk], bh[n][kk], acc[m][n], 0, 0, 0);
          acc[m][n] = __builtin_amdgcn_mfma_f32_16x16x32_bf16(
              ah[m][kk], bl[n][kk], acc[m][n], 0, 0, 0);
          acc[m][n] = __builtin_amdgcn_mfma_f32_16x16x32_bf16(
              ah[m][kk], bh[n][kk], acc[m][n], 0, 0, 0);
        }
    __syncthreads();
  }

  const int rbase = m0 + wr + (lane >> 4) * 4;
  const int cbase = n0 + wc + lr;
#pragma unroll
  for (int m = 0; m < 4; m++)
#pragma unroll
    for (int n = 0; n < 4; n++)
#pragma unroll
      for (int j = 0; j < 4; j++) {
        int s = rbase + m * 16 + j;
        int o = cbase + n * 16;
        O[((size_t)(o >> 6) * M + s) * HD + (o & 63)] = acc[m][n][j];
      }
}

// ---------------------------------------------------------------- plain GEMM (NT)
// mode 2: fp32 out row-major [M][N]
// mode 3: bf16 out as V^T in swizzled tile layout:
//         byte = (o>>6)*PLANE + (s>>6)*TILE + (o&63)*128 + ((2*(s&63)) ^ (((o&63)&7)<<4))
__global__ __launch_bounds__(256) void gemm_nt(
    const unsigned short* __restrict__ A,
    const unsigned short* __restrict__ B0,
    void* O0, int M, int N, int K, int mode)
{
  __shared__ unsigned short As[128 * 64];
  __shared__ unsigned short Bs[128 * 64];
  const unsigned short* B = B0;
  const int m0 = blockIdx.y * 128, n0 = blockIdx.x * 128;
  const int tid = threadIdx.x, wid = tid >> 6, lane = tid & 63;
  const int lr = lane & 15, lk = (lane >> 4) * 8;
  const int wr = (wid >> 1) * 64, wc = (wid & 1) * 64;
  const int strow = lane >> 3;
  const int stcol = (lane & 7) * 8;

  f32x4 acc[4][4];
#pragma unroll
  for (int m = 0; m < 4; m++)
#pragma unroll
    for (int n = 0; n < 4; n++) acc[m][n] = (f32x4){0.f, 0.f, 0.f, 0.f};

  for (int kt = 0; kt < K; kt += 64) {
#pragma unroll
    for (int i = 0; i < 4; i++) {
      int c = wid * 4 + i;
      int row = c * 8 + strow;
      GLL16(A + (size_t)(m0 + row) * K + kt + stcol, &As[c * 512]);
      GLL16(B + (size_t)(n0 + row) * K + kt + stcol, &Bs[c * 512]);
    }
    __syncthreads();
    bf16x8 af[4][2], bfr[4][2];
#pragma unroll
    for (int m = 0; m < 4; m++)
#pragma unroll
      for (int kk = 0; kk < 2; kk++)
        af[m][kk] = *(const bf16x8*)&As[(wr + m * 16 + lr) * 64 + kk * 32 + lk];
#pragma unroll
    for (int n = 0; n < 4; n++)
#pragma unroll
      for (int kk = 0; kk < 2; kk++)
        bfr[n][kk] = *(const bf16x8*)&Bs[(wc + n * 16 + lr) * 64 + kk * 32 + lk];
#pragma unroll
    for (int m = 0; m < 4; m++)
#pragma unroll
      for (int n = 0; n < 4; n++)
#pragma unroll
        for (int kk = 0; kk < 2; kk++)
          acc[m][n] = __builtin_amdgcn_mfma_f32_16x16x32_bf16(
              af[m][kk], bfr[n][kk], acc[m][n], 0, 0, 0);
    __syncthreads();
  }

  const int rbase = m0 + wr + (lane >> 4) * 4;
  const int cbase = n0 + wc + lr;
  if (mode == 3) {
    char* base = (char*)O0;
#pragma unroll
    for (int m = 0; m < 4; m++)
#pragma unroll
      for (int n = 0; n < 4; n++) {
        int s = rbase + m * 16;            // s..s+3, s % 4 == 0
        int o = cbase + n * 16;
        int hd = o >> 6, d = o & 63;
        size_t tb = (size_t)hd * PLANE_BYTES + (size_t)(s >> 6) * TILE_BYTES
                  + (size_t)d * 128;
        int cbyte = (2 * (s & 63)) ^ ((d & 7) << 4);
        u16x4 r;
#pragma unroll
        for (int j = 0; j < 4; j++) r[j] = f2bf(acc[m][n][j]);
        *(u16x4*)(base + tb + cbyte) = r;
      }
  } else {
    float* C = (float*)O0;
#pragma unroll
    for (int m = 0; m < 4; m++)
#pragma unroll
      for (int n = 0; n < 4; n++)
#pragma unroll
        for (int j = 0; j < 4; j++) {
          int s = rbase + m * 16 + j;
          int o = cbase + n * 16;
          C[(size_t)s * N + o] = acc[m][n][j];
        }
  }
}

// ---------------------------------------------------------------- rope apply
// Q: fp32 [head][s][d] -> in-place packed u32 (hi|lo<<16), pre-scaled x8.
// K: fp32 [head][s][d] -> Khi/Klo bf16 planes in swizzled tile layout.
__global__ __launch_bounds__(256) void rope_apply(
    float* __restrict__ Qf, const float* __restrict__ Kf,
    char* __restrict__ Khi, char* __restrict__ Klo,
    const float* __restrict__ cosT, const float* __restrict__ sinT)
{
  int wid = threadIdx.x >> 6, lane = threadIdx.x & 63;
  int row = blockIdx.x * 4 + wid;          // 0 .. NH*S_LEN-1
  int t = row & (S_LEN - 1);
  int head = row >> 12;
  int j = (lane < 32) ? lane : (lane - 32);
  float c = cosT[t * 32 + j], s = sinT[t * 32 + j];
  int partner = (lane < 32) ? (2 * lane + 1) : (2 * (lane - 32));
  float sgn = (lane < 32) ? -1.0f : 1.0f;
  float* qp = Qf + (size_t)row * HD;
  const float* kp = Kf + (size_t)row * HD;
  float q = qp[lane], k = kp[lane];
  float qo = __shfl(q, partner, 64);
  float ko = __shfl(k, partner, 64);
  float qr = (q * c + sgn * qo * s) * 8.0f;   // fold score scale (exact, pow2)
  float kr = k * c + sgn * ko * s;
  unsigned short qhv, qlv, khv, klv;
  split2(qr, qhv, qlv); split2(kr, khv, klv);
  ((unsigned*)qp)[lane] = (unsigned)qhv | ((unsigned)qlv << 16);
  size_t kb = (size_t)head * PLANE_BYTES + (size_t)(t >> 6) * TILE_BYTES
            + (size_t)(t & 63) * 128 + ((2 * lane) ^ ((t & 7) << 4));
  *(unsigned short*)(Khi + kb) = khv;
  *(unsigned short*)(Klo + kb) = klv;
}

// ---------------------------------------------------------------- attention
// Q packed u32 [head][s][d] (pre-scaled x8); Khi/Klo/Vt swizzled tile planes.
// grid (64, 16), 4 waves/block, 16 q rows per wave.
__global__ __launch_bounds__(256, 4) void attn_kernel(
    const unsigned* __restrict__ Q, const char* __restrict__ Khi,
    const char* __restrict__ Klo, const char* __restrict__ Vt,
    unsigned short* __restrict__ Oattn)
{
  __shared__ char KhiL[TILE_BYTES];
  __shared__ char KloL[TILE_BYTES];
  __shared__ char VtL[TILE_BYTES];
  __shared__ unsigned short Ps[4][16 * 72];

  const int h = blockIdx.y;
  const int tid = threadIdx.x, wid = tid >> 6, lane = tid & 63;
  const int lr = lane & 15, hi = lane >> 4, lk = hi * 8;
  const int qw = blockIdx.x * 64 + wid * 16;

  const size_t hoff = (size_t)h * PLANE_BYTES;
  const char* KhiH = Khi + hoff;
  const char* KloH = Klo + hoff;
  const char* VtH  = Vt + hoff;

  const unsigned* Qrow = Q + ((size_t)h * S_LEN + qw + lr) * HD;
  bf16x8 qh[2], ql[2];
  unpack8(&Qrow[lk], qh[0], ql[0]);
  unpack8(&Qrow[32 + lk], qh[1], ql[1]);

  f32x4 acc_o[4];
#pragma unroll
  for (int nb = 0; nb < 4; nb++) acc_o[nb] = (f32x4){0.f, 0.f, 0.f, 0.f};
  float m_r[4], l_r[4];
#pragma unroll
  for (int r = 0; r < 4; r++) { m_r[r] = -__builtin_inff(); l_r[r] = 0.f; }

  for (int kv = 0; kv < S_LEN; kv += 64) {
    const size_t tb = (size_t)(kv >> 6) * TILE_BYTES;
    // ---- stage K hi/lo + V^T via global_load_lds (linear dest, swizzled src) ----
#pragma unroll
    for (int c = 0; c < 2; c++) {
      int ub = c * 4096 + wid * 1024;      // wave-uniform LDS base
      int go = ub + lane * 16;
      GLL16(KhiH + tb + go, KhiL + ub);
      GLL16(KloH + tb + go, KloL + ub);
      GLL16(VtH  + tb + go, VtL  + ub);
    }
    __syncthreads();

    // ---- S = Q K^T (3-term split), swizzled reads ----
    f32x4 accs[4];
#pragma unroll
    for (int jb = 0; jb < 4; jb++) accs[jb] = (f32x4){0.f, 0.f, 0.f, 0.f};
    __builtin_amdgcn_s_setprio(1);
#pragma unroll
    for (int jb = 0; jb < 4; jb++) {
      int krow = jb * 16 + lr;
      int sw = (krow & 7) << 4;
#pragma unroll
      for (int ks = 0; ks < 2; ks++) {
        int addr = krow * 128 + ((ks * 64 + hi * 16) ^ sw);
        bf16x8 kh = *(const bf16x8*)(KhiL + addr);
        bf16x8 kl = *(const bf16x8*)(KloL + addr);
        accs[jb] = __builtin_amdgcn_mfma_f32_16x16x32_bf16(ql[ks], kh, accs[jb], 0, 0, 0);
        accs[jb] = __builtin_amdgcn_mfma_f32_16x16x32_bf16(qh[ks], kl, accs[jb], 0, 0, 0);
        accs[jb] = __builtin_amdgcn_mfma_f32_16x16x32_bf16(qh[ks], kh, accs[jb], 0, 0, 0);
      }
    }
    __builtin_amdgcn_s_setprio(0);

    // ---- online softmax (q row = hi*4+r, kv col = jb*16+lr); scores pre-scaled ----
    float alpha[4];
#pragma unroll
    for (int r = 0; r < 4; r++) {
      float mx = fmaxf(fmaxf(accs[0][r], accs[1][r]), fmaxf(accs[2][r], accs[3][r]));
      mx = fmaxf(mx, __shfl_xor(mx, 1));
      mx = fmaxf(mx, __shfl_xor(mx, 2));
      mx = fmaxf(mx, __shfl_xor(mx, 4));
      mx = fmaxf(mx, __shfl_xor(mx, 8));
      float mnew = fmaxf(m_r[r], mx);
      alpha[r] = __expf(m_r[r] - mnew);
      m_r[r] = mnew;
    }
    float rs[4] = {0.f, 0.f, 0.f, 0.f};
#pragma unroll
    for (int jb = 0; jb < 4; jb++)
#pragma unroll
      for (int r = 0; r < 4; r++) {
        float p = __expf(accs[jb][r] - m_r[r]);
        rs[r] += p;
        Ps[wid][(hi * 4 + r) * 72 + jb * 16 + lr] = f2bf(p);
      }
#pragma unroll
    for (int r = 0; r < 4; r++) {
      float t = rs[r];
      t += __shfl_xor(t, 1);
      t += __shfl_xor(t, 2);
      t += __shfl_xor(t, 4);
      t += __shfl_xor(t, 8);
      l_r[r] = l_r[r] * alpha[r] + t;
    }
#pragma unroll
    for (int nb = 0; nb < 4; nb++)
#pragma unroll
      for (int r = 0; r < 4; r++) acc_o[nb][r] *= alpha[r];

    // ---- O += P V (V^T swizzled reads) ----
    __builtin_amdgcn_s_setprio(1);
#pragma unroll
    for (int ks = 0; ks < 2; ks++) {
      bf16x8 pa = *(const bf16x8*)&Ps[wid][lr * 72 + ks * 32 + lk];
#pragma unroll
      for (int nb = 0; nb < 4; nb++) {
        int vrow = nb * 16 + lr;
        int vaddr = vrow * 128 + ((ks * 64 + hi * 16) ^ ((vrow & 7) << 4));
        bf16x8 bv = *(const bf16x8*)(VtL + vaddr);
        acc_o[nb] = __builtin_amdgcn_mfma_f32_16x16x32_bf16(pa, bv, acc_o[nb], 0, 0, 0);
      }
    }
    __builtin_amdgcn_s_setprio(0);
    __syncthreads();
  }

  // ---- epilogue ----
#pragma unroll
  for (int nb = 0; nb < 4; nb++)
#pragma unroll
    for (int r = 0; r < 4; r++) {
      float v = acc_o[nb][r] / l_r[r];
      int s = qw + hi * 4 + r;
      int col = h * HD + nb * 16 + lr;
      Oattn[(size_t)s * 1024 + col] = f2bf(v);
    }
}

// ---------------------------------------------------------------- launch
extern "C" void kernel_launch(void* const* d_in, const int* in_sizes, int n_in,
                              void* d_out, int out_size, void* d_ws, size_t ws_size,
                              hipStream_t stream)
{
  const float* hs = (const float*)d_in[0];
  const float* Wq = (const float*)d_in[1];
  const float* Wk = (const float*)d_in[2];
  const float* Wv = (const float*)d_in[3];
  const float* Wo = (const float*)d_in[4];

  char* ws = (char*)d_ws;
  const size_t HS = (size_t)S_LEN * 1024;      // 4194304 elems
  const size_t WN = (size_t)1024 * 1024;
  size_t off = 0;
  unsigned short* hsh = (unsigned short*)(ws + off); off += HS * 2;   // Klo alias later
  unsigned short* hsl = (unsigned short*)(ws + off); off += HS * 2;   // Khi alias later
  unsigned short* wqh = (unsigned short*)(ws + off); off += WN * 2;   // Ab alias later
  unsigned short* wql = (unsigned short*)(ws + off); off += WN * 2;
  unsigned short* wkh = (unsigned short*)(ws + off); off += WN * 2;
  unsigned short* wkl = (unsigned short*)(ws + off); off += WN * 2;
  unsigned short* wvb = (unsigned short*)(ws + off); off += WN * 2;
  unsigned short* wob = (unsigned short*)(ws + off); off += WN * 2;
  float* Qf = (float*)(ws + off); off += HS * 4;     // becomes packed u32
  float* Kf = (float*)(ws + off); off += HS * 4;
  char* VT_g = ws + off; off += (size_t)NH * PLANE_BYTES;             // 8MB
  float* cosT = (float*)(ws + off); off += (size_t)S_LEN * 32 * 4;
  float* sinT = (float*)(ws + off); off += (size_t)S_LEN * 32 * 4;
  // aliases (regions dead by the time they're written):
  char* Khi_g = (char*)hsl;            // dead after gemm_split
  char* Klo_g = (char*)hsh;            // dead after V projection
  unsigned short* Ab = wqh;            // wqh..wkl (8MB), dead after gemm_split

  cvt_kernel<<<4096, 256, 0, stream>>>(hs, Wq, Wk, Wv, Wo,
                                       hsh, hsl, wqh, wql, wkh, wkl, wvb, wob);

  double base = 10000.0 * pow((double)S_LEN / 2048.0, 64.0 / 62.0);
  rope_table<<<(S_LEN * 32 + 255) / 256, 256, 0, stream>>>(cosT, sinT, base);

  gemm_split<<<dim3(8, 32, 2), 256, 0, stream>>>(
      hsh, hsl, wqh, wql, wkh, wkl, Qf, Kf, S_LEN, 1024);

  gemm_nt<<<dim3(8, 32, 1), 256, 0, stream>>>(
      hsh, wvb, VT_g, S_LEN, 1024, 1024, 3);

  rope_apply<<<NH * S_LEN / 4, 256, 0, stream>>>(
      Qf, Kf, Khi_g, Klo_g, cosT, sinT);

  attn_kernel<<<dim3(S_LEN / 64, NH), 256, 0, stream>>>(
      (const unsigned*)Qf, Khi_g, Klo_g, VT_g, Ab);

  gemm_nt<<<dim3(8, 32, 1), 256, 0, stream>>>(
      Ab, wob, d_out, S_LEN, 1024, 1024, 2);
}

// Round 4
// 327.779 us; speedup vs baseline: 1.4495x; 1.2353x over previous
//
#include <hip/hip_runtime.h>
#include <cmath>
#include <cstdint>

#define S_LEN 4096
#define NH 16
#define HD 64

typedef __attribute__((ext_vector_type(8))) short bf16x8;
typedef __attribute__((ext_vector_type(4))) float f32x4;
typedef __attribute__((ext_vector_type(16))) float f32x16;
typedef __attribute__((ext_vector_type(4))) unsigned short u16x4;
typedef __attribute__((ext_vector_type(4))) unsigned int u32x4;
typedef __attribute__((ext_vector_type(4))) float f4;

__device__ __forceinline__ unsigned short f2bf(float f) {
  union { float f; unsigned u; } v; v.f = f;
  unsigned u = v.u;
  u += 0x7FFFu + ((u >> 16) & 1u);
  return (unsigned short)(u >> 16);
}
__device__ __forceinline__ float bf2f(unsigned short h) {
  union { unsigned u; float f; } v; v.u = ((unsigned)h) << 16;
  return v.f;
}
__device__ __forceinline__ void split2(float x, unsigned short& h, unsigned short& l) {
  h = f2bf(x);
  l = f2bf(x - bf2f(h));
}
__device__ __forceinline__ void unpack8(const unsigned* p, bf16x8& hi, bf16x8& lo) {
  u32x4 a = *(const u32x4*)p;
  u32x4 b = *(const u32x4*)(p + 4);
#pragma unroll
  for (int i = 0; i < 4; i++) {
    hi[i]     = (short)(a[i] & 0xFFFFu);
    lo[i]     = (short)(a[i] >> 16);
    hi[4 + i] = (short)(b[i] & 0xFFFFu);
    lo[4 + i] = (short)(b[i] >> 16);
  }
}
__device__ __forceinline__ float permx32(float v) {
  int idx = (((int)(threadIdx.x & 63)) ^ 32) << 2;
  return __int_as_float(__builtin_amdgcn_ds_bpermute(idx, __float_as_int(v)));
}
__device__ __forceinline__ unsigned permx32u(unsigned v) {
  int idx = (((int)(threadIdx.x & 63)) ^ 32) << 2;
  return (unsigned)__builtin_amdgcn_ds_bpermute(idx, (int)v);
}
// packs: low16 = bf16(a), high16 = bf16(b)
__device__ __forceinline__ unsigned pack2(float a, float b) {
  unsigned r;
  asm("v_cvt_pk_bf16_f32 %0, %1, %2" : "=v"(r) : "v"(a), "v"(b));
  return r;
}

#define GLL16(g, l) __builtin_amdgcn_global_load_lds( \
    (const __attribute__((address_space(1))) void*)(g), \
    (__attribute__((address_space(3))) void*)(l), 16, 0, 0)

// per-head byte size of a swizzled-tile plane: 4096 rows * 128B
#define PLANE_BYTES 524288
// one 64x64 bf16 tile: 8KB
#define TILE_BYTES 8192

// ---------------------------------------------------------------- convert
__global__ __launch_bounds__(256) void cvt_kernel(
    const float* __restrict__ hs, const float* __restrict__ wq,
    const float* __restrict__ wk, const float* __restrict__ wv,
    const float* __restrict__ wo,
    unsigned short* __restrict__ hsh, unsigned short* __restrict__ hsl,
    unsigned short* __restrict__ wqh, unsigned short* __restrict__ wql,
    unsigned short* __restrict__ wkh, unsigned short* __restrict__ wkl,
    unsigned short* __restrict__ wvb, unsigned short* __restrict__ wob)
{
  const int HID4 = (S_LEN * 1024) / 4;
  const int W4   = (1024 * 1024) / 4;
  const int total = HID4 + 4 * W4;
  for (int i = blockIdx.x * 256 + threadIdx.x; i < total;
       i += gridDim.x * 256) {
    const float* s; unsigned short *dh, *dl; int off;
    if (i < HID4) { s = hs; dh = hsh; dl = hsl; off = i; }
    else {
      int j = i - HID4; int w = j >> 18; off = j & (W4 - 1);
      if (w == 0)      { s = wq; dh = wqh; dl = wql; }
      else if (w == 1) { s = wk; dh = wkh; dl = wkl; }
      else if (w == 2) { s = wv; dh = wvb; dl = nullptr; }
      else             { s = wo; dh = wob; dl = nullptr; }
    }
    f4 v = *(const f4*)(s + (size_t)off * 4);
    u16x4 rh, rl;
#pragma unroll
    for (int j = 0; j < 4; j++) {
      unsigned short h, l; split2(v[j], h, l);
      rh[j] = h; rl[j] = l;
    }
    *(u16x4*)(dh + (size_t)off * 4) = rh;
    if (dl) *(u16x4*)(dl + (size_t)off * 4) = rl;
  }
}

// ---------------------------------------------------------------- rope table
__global__ __launch_bounds__(256) void rope_table(
    float* __restrict__ cosT, float* __restrict__ sinT, double base)
{
  int idx = blockIdx.x * 256 + threadIdx.x;
  if (idx >= S_LEN * 32) return;
  int t = idx >> 5, j = idx & 31;
  double invf = pow(base, -(double)j / 32.0);
  double f = fmod((double)t * invf, 6.283185307179586476925286766559);
  float ff = (float)f;
  cosT[idx] = cosf(ff);
  sinT[idx] = sinf(ff);
}

// ---------------------------------------------------------------- split GEMM (NT)
__global__ __launch_bounds__(256) void gemm_split(
    const unsigned short* __restrict__ Ah, const unsigned short* __restrict__ Al,
    const unsigned short* __restrict__ Bh0, const unsigned short* __restrict__ Bl0,
    const unsigned short* __restrict__ Bh1, const unsigned short* __restrict__ Bl1,
    float* O0, float* O1, int M, int K)
{
  __shared__ unsigned short Ash[128 * 64];
  __shared__ unsigned short Asl[128 * 64];
  __shared__ unsigned short Bsh[128 * 64];
  __shared__ unsigned short Bsl[128 * 64];
  const unsigned short* Bh = blockIdx.z ? Bh1 : Bh0;
  const unsigned short* Bl = blockIdx.z ? Bl1 : Bl0;
  float* O = blockIdx.z ? O1 : O0;
  const int m0 = blockIdx.y * 128, n0 = blockIdx.x * 128;
  const int tid = threadIdx.x, wid = tid >> 6, lane = tid & 63;
  const int lr = lane & 15, lk = (lane >> 4) * 8;
  const int wr = (wid >> 1) * 64, wc = (wid & 1) * 64;
  const int strow = lane >> 3;
  const int stcol = (lane & 7) * 8;

  f32x4 acc[4][4];
#pragma unroll
  for (int m = 0; m < 4; m++)
#pragma unroll
    for (int n = 0; n < 4; n++) acc[m][n] = (f32x4){0.f, 0.f, 0.f, 0.f};

  for (int kt = 0; kt < K; kt += 64) {
#pragma unroll
    for (int i = 0; i < 4; i++) {
      int c = wid * 4 + i;
      int row = c * 8 + strow;
      GLL16(Ah + (size_t)(m0 + row) * K + kt + stcol, &Ash[c * 512]);
      GLL16(Al + (size_t)(m0 + row) * K + kt + stcol, &Asl[c * 512]);
      GLL16(Bh + (size_t)(n0 + row) * K + kt + stcol, &Bsh[c * 512]);
      GLL16(Bl + (size_t)(n0 + row) * K + kt + stcol, &Bsl[c * 512]);
    }
    __syncthreads();
    bf16x8 ah[4][2], al[4][2], bh[4][2], bl[4][2];
#pragma unroll
    for (int m = 0; m < 4; m++)
#pragma unroll
      for (int kk = 0; kk < 2; kk++) {
        ah[m][kk] = *(const bf16x8*)&Ash[(wr + m * 16 + lr) * 64 + kk * 32 + lk];
        al[m][kk] = *(const bf16x8*)&Asl[(wr + m * 16 + lr) * 64 + kk * 32 + lk];
      }
#pragma unroll
    for (int n = 0; n < 4; n++)
#pragma unroll
      for (int kk = 0; kk < 2; kk++) {
        bh[n][kk] = *(const bf16x8*)&Bsh[(wc + n * 16 + lr) * 64 + kk * 32 + lk];
        bl[n][kk] = *(const bf16x8*)&Bsl[(wc + n * 16 + lr) * 64 + kk * 32 + lk];
      }
#pragma unroll
    for (int m = 0; m < 4; m++)
#pragma unroll
      for (int n = 0; n < 4; n++)
#pragma unroll
        for (int kk = 0; kk < 2; kk++) {
          acc[m][n] = __builtin_amdgcn_mfma_f32_16x16x32_bf16(
              al[m][kk], bh[n][kk], acc[m][n], 0, 0, 0);
          acc[m][n] = __builtin_amdgcn_mfma_f32_16x16x32_bf16(
              ah[m][kk], bl[n][kk], acc[m][n], 0, 0, 0);
          acc[m][n] = __builtin_amdgcn_mfma_f32_16x16x32_bf16(
              ah[m][kk], bh[n][kk], acc[m][n], 0, 0, 0);
        }
    __syncthreads();
  }

  const int rbase = m0 + wr + (lane >> 4) * 4;
  const int cbase = n0 + wc + lr;
#pragma unroll
  for (int m = 0; m < 4; m++)
#pragma unroll
    for (int n = 0; n < 4; n++)
#pragma unroll
      for (int j = 0; j < 4; j++) {
        int s = rbase + m * 16 + j;
        int o = cbase + n * 16;
        O[((size_t)(o >> 6) * M + s) * HD + (o & 63)] = acc[m][n][j];
      }
}

// ---------------------------------------------------------------- plain GEMM (NT)
// mode 2: fp32 out row-major [M][N]
// mode 3: bf16 out as V^T in swizzled tile layout
__global__ __launch_bounds__(256) void gemm_nt(
    const unsigned short* __restrict__ A,
    const unsigned short* __restrict__ B0,
    void* O0, int M, int N, int K, int mode)
{
  __shared__ unsigned short As[128 * 64];
  __shared__ unsigned short Bs[128 * 64];
  const unsigned short* B = B0;
  const int m0 = blockIdx.y * 128, n0 = blockIdx.x * 128;
  const int tid = threadIdx.x, wid = tid >> 6, lane = tid & 63;
  const int lr = lane & 15, lk = (lane >> 4) * 8;
  const int wr = (wid >> 1) * 64, wc = (wid & 1) * 64;
  const int strow = lane >> 3;
  const int stcol = (lane & 7) * 8;

  f32x4 acc[4][4];
#pragma unroll
  for (int m = 0; m < 4; m++)
#pragma unroll
    for (int n = 0; n < 4; n++) acc[m][n] = (f32x4){0.f, 0.f, 0.f, 0.f};

  for (int kt = 0; kt < K; kt += 64) {
#pragma unroll
    for (int i = 0; i < 4; i++) {
      int c = wid * 4 + i;
      int row = c * 8 + strow;
      GLL16(A + (size_t)(m0 + row) * K + kt + stcol, &As[c * 512]);
      GLL16(B + (size_t)(n0 + row) * K + kt + stcol, &Bs[c * 512]);
    }
    __syncthreads();
    bf16x8 af[4][2], bfr[4][2];
#pragma unroll
    for (int m = 0; m < 4; m++)
#pragma unroll
      for (int kk = 0; kk < 2; kk++)
        af[m][kk] = *(const bf16x8*)&As[(wr + m * 16 + lr) * 64 + kk * 32 + lk];
#pragma unroll
    for (int n = 0; n < 4; n++)
#pragma unroll
      for (int kk = 0; kk < 2; kk++)
        bfr[n][kk] = *(const bf16x8*)&Bs[(wc + n * 16 + lr) * 64 + kk * 32 + lk];
#pragma unroll
    for (int m = 0; m < 4; m++)
#pragma unroll
      for (int n = 0; n < 4; n++)
#pragma unroll
        for (int kk = 0; kk < 2; kk++)
          acc[m][n] = __builtin_amdgcn_mfma_f32_16x16x32_bf16(
              af[m][kk], bfr[n][kk], acc[m][n], 0, 0, 0);
    __syncthreads();
  }

  const int rbase = m0 + wr + (lane >> 4) * 4;
  const int cbase = n0 + wc + lr;
  if (mode == 3) {
    char* base = (char*)O0;
#pragma unroll
    for (int m = 0; m < 4; m++)
#pragma unroll
      for (int n = 0; n < 4; n++) {
        int s = rbase + m * 16;
        int o = cbase + n * 16;
        int hd = o >> 6, d = o & 63;
        size_t tb = (size_t)hd * PLANE_BYTES + (size_t)(s >> 6) * TILE_BYTES
                  + (size_t)d * 128;
        int cbyte = (2 * (s & 63)) ^ ((d & 7) << 4);
        u16x4 r;
#pragma unroll
        for (int j = 0; j < 4; j++) r[j] = f2bf(acc[m][n][j]);
        *(u16x4*)(base + tb + cbyte) = r;
      }
  } else {
    float* C = (float*)O0;
#pragma unroll
    for (int m = 0; m < 4; m++)
#pragma unroll
      for (int n = 0; n < 4; n++)
#pragma unroll
        for (int j = 0; j < 4; j++) {
          int s = rbase + m * 16 + j;
          int o = cbase + n * 16;
          C[(size_t)s * N + o] = acc[m][n][j];
        }
  }
}

// ---------------------------------------------------------------- rope apply
__global__ __launch_bounds__(256) void rope_apply(
    float* __restrict__ Qf, const float* __restrict__ Kf,
    char* __restrict__ Khi, char* __restrict__ Klo,
    const float* __restrict__ cosT, const float* __restrict__ sinT)
{
  int wid = threadIdx.x >> 6, lane = threadIdx.x & 63;
  int row = blockIdx.x * 4 + wid;
  int t = row & (S_LEN - 1);
  int head = row >> 12;
  int j = (lane < 32) ? lane : (lane - 32);
  float c = cosT[t * 32 + j], s = sinT[t * 32 + j];
  int partner = (lane < 32) ? (2 * lane + 1) : (2 * (lane - 32));
  float sgn = (lane < 32) ? -1.0f : 1.0f;
  float* qp = Qf + (size_t)row * HD;
  const float* kp = Kf + (size_t)row * HD;
  float q = qp[lane], k = kp[lane];
  float qo = __shfl(q, partner, 64);
  float ko = __shfl(k, partner, 64);
  float qr = (q * c + sgn * qo * s) * 8.0f;
  float kr = k * c + sgn * ko * s;
  unsigned short qhv, qlv, khv, klv;
  split2(qr, qhv, qlv); split2(kr, khv, klv);
  ((unsigned*)qp)[lane] = (unsigned)qhv | ((unsigned)qlv << 16);
  size_t kb = (size_t)head * PLANE_BYTES + (size_t)(t >> 6) * TILE_BYTES
            + (size_t)(t & 63) * 128 + ((2 * lane) ^ ((t & 7) << 4));
  *(unsigned short*)(Khi + kb) = khv;
  *(unsigned short*)(Klo + kb) = klv;
}

// ---------------------------------------------------------------- attention
// Swapped-operand flash attention, 32x32 MFMA.
// Q packed u32 [head][s][d] (pre-scaled x8); Khi/Klo/Vt swizzled tile planes.
// grid (32, 16) [flat-swizzled so one head's blocks share an XCD].
// 4 waves/block; each wave owns 32 q rows (q = qw + (lane&31)).
__global__ __launch_bounds__(256) void attn_kernel(
    const unsigned* __restrict__ Q, const char* __restrict__ Khi,
    const char* __restrict__ Klo, const char* __restrict__ Vt,
    unsigned short* __restrict__ Oattn)
{
  __shared__ char KhiL[2][TILE_BYTES];
  __shared__ char KloL[2][TILE_BYTES];
  __shared__ char VtL[2][TILE_BYTES];

  const int tid = threadIdx.x, wid = tid >> 6, lane = tid & 63;
  const int l5 = lane & 31, hi2 = lane >> 5;
  const bool lohalf = (hi2 == 0);

  // head->XCD swizzle: heads {x, x+8} live on XCD x
  int id = blockIdx.x + 32 * blockIdx.y;          // dispatch-linear
  int h  = (id & 7) + 8 * ((id >> 3) & 1);
  int bx = id >> 4;                               // 0..31
  const int qw = bx * 128 + wid * 32;

  const size_t hoff = (size_t)h * PLANE_BYTES;
  const char* KhiH = Khi + hoff;
  const char* KloH = Klo + hoff;
  const char* VtH  = Vt + hoff;

  // Q fragments: B-operand, col = q = qw + l5, k-chunk d = 16ks+8hi2+i
  const unsigned* Qrow = Q + ((size_t)h * S_LEN + qw + l5) * HD;
  bf16x8 qh[4], ql[4];
#pragma unroll
  for (int ks = 0; ks < 4; ks++) unpack8(&Qrow[ks * 16 + hi2 * 8], qh[ks], ql[ks]);

  f32x16 acc_o0 = (f32x16)0.0f, acc_o1 = (f32x16)0.0f;
  float m_q = -__builtin_inff(), l_q = 0.f;

#define STAGE(kt, b) do { \
    size_t tb = (size_t)(kt) * TILE_BYTES; \
    _Pragma("unroll") \
    for (int c = 0; c < 2; c++) { \
      int ub = c * 4096 + wid * 1024; \
      int go = ub + lane * 16; \
      GLL16(KhiH + tb + go, &KhiL[b][ub]); \
      GLL16(KloH + tb + go, &KloL[b][ub]); \
      GLL16(VtH + tb + go, &VtL[b][ub]); \
    } } while (0)

  STAGE(0, 0);

  for (int kt = 0; kt < S_LEN / 64; ++kt) {
    const int cur = kt & 1;
    if (kt < S_LEN / 64 - 1) {
      STAGE(kt + 1, cur ^ 1);
      asm volatile("s_waitcnt vmcnt(6)" ::: "memory");
    } else {
      asm volatile("s_waitcnt vmcnt(0)" ::: "memory");
    }
    __builtin_amdgcn_s_barrier();
    asm volatile("" ::: "memory");

    // ---- S^T = K Q (3-term split): rows kv, cols q ----
    f32x16 s0 = (f32x16)0.0f, s1 = (f32x16)0.0f;
    __builtin_amdgcn_s_setprio(1);
#pragma unroll
    for (int ks = 0; ks < 4; ks++) {
      const int coff = (32 * ks + 16 * hi2) ^ ((l5 & 7) << 4);
      bf16x8 kh0 = *(const bf16x8*)(&KhiL[cur][l5 * 128 + coff]);
      bf16x8 kl0 = *(const bf16x8*)(&KloL[cur][l5 * 128 + coff]);
      bf16x8 kh1 = *(const bf16x8*)(&KhiL[cur][(32 + l5) * 128 + coff]);
      bf16x8 kl1 = *(const bf16x8*)(&KloL[cur][(32 + l5) * 128 + coff]);
      s0 = __builtin_amdgcn_mfma_f32_32x32x16_bf16(kh0, ql[ks], s0, 0, 0, 0);
      s0 = __builtin_amdgcn_mfma_f32_32x32x16_bf16(kl0, qh[ks], s0, 0, 0, 0);
      s0 = __builtin_amdgcn_mfma_f32_32x32x16_bf16(kh0, qh[ks], s0, 0, 0, 0);
      s1 = __builtin_amdgcn_mfma_f32_32x32x16_bf16(kh1, ql[ks], s1, 0, 0, 0);
      s1 = __builtin_amdgcn_mfma_f32_32x32x16_bf16(kl1, qh[ks], s1, 0, 0, 0);
      s1 = __builtin_amdgcn_mfma_f32_32x32x16_bf16(kh1, qh[ks], s1, 0, 0, 0);
    }
    __builtin_amdgcn_s_setprio(0);

    // ---- per-lane online softmax (q = qw + l5) ----
    float mx = fmaxf(s0[0], s0[1]);
#pragma unroll
    for (int r = 2; r < 16; r++) mx = fmaxf(mx, s0[r]);
#pragma unroll
    for (int r = 0; r < 16; r++) mx = fmaxf(mx, s1[r]);
    mx = fmaxf(mx, permx32(mx));
    float mnew = fmaxf(m_q, mx);
    float alpha = __expf(m_q - mnew);
    m_q = mnew;

    float p[32];
    float rs = 0.f;
#pragma unroll
    for (int r = 0; r < 16; r++) { p[r] = __expf(s0[r] - mnew); rs += p[r]; }
#pragma unroll
    for (int r = 0; r < 16; r++) { p[16 + r] = __expf(s1[r] - mnew); rs += p[16 + r]; }
    rs += permx32(rs);
    l_q = l_q * alpha + rs;
#pragma unroll
    for (int i = 0; i < 16; i++) { acc_o0[i] *= alpha; acc_o1[i] *= alpha; }

    // ---- build P fragments (B-operand for PV), in-register exchange ----
    bf16x8 pf[4];
#pragma unroll
    for (int ks = 0; ks < 4; ks++) {
      const int ib = (ks >> 1) * 16 + (ks & 1) * 8;
      unsigned a0 = pack2(p[ib + 0], p[ib + 1]);
      unsigned a1 = pack2(p[ib + 2], p[ib + 3]);
      unsigned b0 = pack2(p[ib + 4], p[ib + 5]);
      unsigned b1 = pack2(p[ib + 6], p[ib + 7]);
      unsigned sw0 = permx32u(lohalf ? b0 : a0);
      unsigned sw1 = permx32u(lohalf ? b1 : a1);
      u32x4 w;
      w[0] = lohalf ? a0 : sw0;
      w[1] = lohalf ? a1 : sw1;
      w[2] = lohalf ? sw0 : b0;
      w[3] = lohalf ? sw1 : b1;
      union { u32x4 u; bf16x8 b; } cv; cv.u = w;
      pf[ks] = cv.b;
    }

    // ---- O^T += V^T P : rows d, cols q ----
    __builtin_amdgcn_s_setprio(1);
#pragma unroll
    for (int ks = 0; ks < 4; ks++) {
      const int coff = (32 * ks + 16 * hi2) ^ ((l5 & 7) << 4);
      bf16x8 v0 = *(const bf16x8*)(&VtL[cur][l5 * 128 + coff]);
      bf16x8 v1 = *(const bf16x8*)(&VtL[cur][(32 + l5) * 128 + coff]);
      acc_o0 = __builtin_amdgcn_mfma_f32_32x32x16_bf16(v0, pf[ks], acc_o0, 0, 0, 0);
      acc_o1 = __builtin_amdgcn_mfma_f32_32x32x16_bf16(v1, pf[ks], acc_o1, 0, 0, 0);
    }
    __builtin_amdgcn_s_setprio(0);

    asm volatile("" ::: "memory");
    __builtin_amdgcn_s_barrier();
    asm volatile("" ::: "memory");
  }
#undef STAGE

  // ---- epilogue: lane holds O^T[d=crow(r,hi2)+32dt][q=qw+l5], scale 1/l ----
  const float inv = 1.0f / l_q;
  unsigned* orow = (unsigned*)(Oattn + (size_t)(qw + l5) * 1024 + h * HD);
#pragma unroll
  for (int k = 0; k < 8; k++) {
    const int d0 = 2 * (k & 1) + 8 * (k >> 1) + 4 * hi2;   // even d, pair (d0, d0+1)
    unsigned w0 = (unsigned)f2bf(acc_o0[2 * k] * inv)
                | ((unsigned)f2bf(acc_o0[2 * k + 1] * inv) << 16);
    unsigned w1 = (unsigned)f2bf(acc_o1[2 * k] * inv)
                | ((unsigned)f2bf(acc_o1[2 * k + 1] * inv) << 16);
    orow[d0 >> 1] = w0;
    orow[(d0 + 32) >> 1] = w1;
  }
}

// ---------------------------------------------------------------- launch
extern "C" void kernel_launch(void* const* d_in, const int* in_sizes, int n_in,
                              void* d_out, int out_size, void* d_ws, size_t ws_size,
                              hipStream_t stream)
{
  const float* hs = (const float*)d_in[0];
  const float* Wq = (const float*)d_in[1];
  const float* Wk = (const float*)d_in[2];
  const float* Wv = (const float*)d_in[3];
  const float* Wo = (const float*)d_in[4];

  char* ws = (char*)d_ws;
  const size_t HS = (size_t)S_LEN * 1024;
  const size_t WN = (size_t)1024 * 1024;
  size_t off = 0;
  unsigned short* hsh = (unsigned short*)(ws + off); off += HS * 2;   // Klo alias later
  unsigned short* hsl = (unsigned short*)(ws + off); off += HS * 2;   // Khi alias later
  unsigned short* wqh = (unsigned short*)(ws + off); off += WN * 2;   // Ab alias later
  unsigned short* wql = (unsigned short*)(ws + off); off += WN * 2;
  unsigned short* wkh = (unsigned short*)(ws + off); off += WN * 2;
  unsigned short* wkl = (unsigned short*)(ws + off); off += WN * 2;
  unsigned short* wvb = (unsigned short*)(ws + off); off += WN * 2;
  unsigned short* wob = (unsigned short*)(ws + off); off += WN * 2;
  float* Qf = (float*)(ws + off); off += HS * 4;     // becomes packed u32
  float* Kf = (float*)(ws + off); off += HS * 4;
  char* VT_g = ws + off; off += (size_t)NH * PLANE_BYTES;
  float* cosT = (float*)(ws + off); off += (size_t)S_LEN * 32 * 4;
  float* sinT = (float*)(ws + off); off += (size_t)S_LEN * 32 * 4;
  char* Khi_g = (char*)hsl;            // dead after gemm_split
  char* Klo_g = (char*)hsh;            // dead after V projection
  unsigned short* Ab = wqh;            // 8MB region, dead after gemm_split

  cvt_kernel<<<4096, 256, 0, stream>>>(hs, Wq, Wk, Wv, Wo,
                                       hsh, hsl, wqh, wql, wkh, wkl, wvb, wob);

  double base = 10000.0 * pow((double)S_LEN / 2048.0, 64.0 / 62.0);
  rope_table<<<(S_LEN * 32 + 255) / 256, 256, 0, stream>>>(cosT, sinT, base);

  gemm_split<<<dim3(8, 32, 2), 256, 0, stream>>>(
      hsh, hsl, wqh, wql, wkh, wkl, Qf, Kf, S_LEN, 1024);

  gemm_nt<<<dim3(8, 32, 1), 256, 0, stream>>>(
      hsh, wvb, VT_g, S_LEN, 1024, 1024, 3);

  rope_apply<<<NH * S_LEN / 4, 256, 0, stream>>>(
      Qf, Kf, Khi_g, Klo_g, cosT, sinT);

  attn_kernel<<<dim3(32, 16), 256, 0, stream>>>(
      (const unsigned*)Qf, Khi_g, Klo_g, VT_g, Ab);

  gemm_nt<<<dim3(8, 32, 1), 256, 0, stream>>>(
      Ab, wob, d_out, S_LEN, 1024, 1024, 2);
}

// Round 5
// 284.699 us; speedup vs baseline: 1.6688x; 1.1513x over previous
//
#include <hip/hip_runtime.h>
#include <cmath>
#include <cstdint>

#define S_LEN 4096
#define NH 16
#define HD 64

typedef __attribute__((ext_vector_type(8))) short bf16x8;
typedef _Float16 f16x8 __attribute__((ext_vector_type(8)));
typedef __attribute__((ext_vector_type(4))) float f32x4;
typedef __attribute__((ext_vector_type(16))) float f32x16;
typedef __attribute__((ext_vector_type(4))) unsigned short u16x4;
typedef __attribute__((ext_vector_type(4))) unsigned int u32x4;
typedef __attribute__((ext_vector_type(4))) float f4;

__device__ __forceinline__ unsigned short f2bf(float f) {
  union { float f; unsigned u; } v; v.f = f;
  unsigned u = v.u;
  u += 0x7FFFu + ((u >> 16) & 1u);
  return (unsigned short)(u >> 16);
}
__device__ __forceinline__ float bf2f(unsigned short h) {
  union { unsigned u; float f; } v; v.u = ((unsigned)h) << 16;
  return v.f;
}
__device__ __forceinline__ void split2(float x, unsigned short& h, unsigned short& l) {
  h = f2bf(x);
  l = f2bf(x - bf2f(h));
}
__device__ __forceinline__ unsigned short f2h(float x) {
  union { _Float16 h; unsigned short u; } v; v.h = (_Float16)x; return v.u;
}
__device__ __forceinline__ float permx32(float v) {
  int idx = (((int)(threadIdx.x & 63)) ^ 32) << 2;
  return __int_as_float(__builtin_amdgcn_ds_bpermute(idx, __float_as_int(v)));
}
__device__ __forceinline__ unsigned permx32u(unsigned v) {
  int idx = (((int)(threadIdx.x & 63)) ^ 32) << 2;
  return (unsigned)__builtin_amdgcn_ds_bpermute(idx, (int)v);
}
__device__ __forceinline__ float exp2a(float x) {
  float r; asm("v_exp_f32 %0, %1" : "=v"(r) : "v"(x)); return r;
}
// packs: low16 = f16(a), high16 = f16(b), round-toward-zero
__device__ __forceinline__ unsigned pkh(float a, float b) {
  unsigned r;
  asm("v_cvt_pkrtz_f16_f32 %0, %1, %2" : "=v"(r) : "v"(a), "v"(b));
  return r;
}

#define GLL16(g, l) __builtin_amdgcn_global_load_lds( \
    (const __attribute__((address_space(1))) void*)(g), \
    (__attribute__((address_space(3))) void*)(l), 16, 0, 0)

// per-head byte size of a swizzled-tile plane: 4096 rows * 128B
#define PLANE_BYTES 524288
// one 64x64 2-byte tile: 8KB
#define TILE_BYTES 8192

// ---------------------------------------------------------------- convert
__global__ __launch_bounds__(256) void cvt_kernel(
    const float* __restrict__ hs, const float* __restrict__ wq,
    const float* __restrict__ wk, const float* __restrict__ wv,
    const float* __restrict__ wo,
    unsigned short* __restrict__ hsh, unsigned short* __restrict__ hsl,
    unsigned short* __restrict__ wqh, unsigned short* __restrict__ wql,
    unsigned short* __restrict__ wkh, unsigned short* __restrict__ wkl,
    unsigned short* __restrict__ wvb, unsigned short* __restrict__ wob)
{
  const int HID4 = (S_LEN * 1024) / 4;
  const int W4   = (1024 * 1024) / 4;
  const int total = HID4 + 4 * W4;
  for (int i = blockIdx.x * 256 + threadIdx.x; i < total;
       i += gridDim.x * 256) {
    const float* s; unsigned short *dh, *dl; int off;
    if (i < HID4) { s = hs; dh = hsh; dl = hsl; off = i; }
    else {
      int j = i - HID4; int w = j >> 18; off = j & (W4 - 1);
      if (w == 0)      { s = wq; dh = wqh; dl = wql; }
      else if (w == 1) { s = wk; dh = wkh; dl = wkl; }
      else if (w == 2) { s = wv; dh = wvb; dl = nullptr; }
      else             { s = wo; dh = wob; dl = nullptr; }
    }
    f4 v = *(const f4*)(s + (size_t)off * 4);
    u16x4 rh, rl;
#pragma unroll
    for (int j = 0; j < 4; j++) {
      unsigned short h, l; split2(v[j], h, l);
      rh[j] = h; rl[j] = l;
    }
    *(u16x4*)(dh + (size_t)off * 4) = rh;
    if (dl) *(u16x4*)(dl + (size_t)off * 4) = rl;
  }
}

// ---------------------------------------------------------------- rope table
__global__ __launch_bounds__(256) void rope_table(
    float* __restrict__ cosT, float* __restrict__ sinT, double base)
{
  int idx = blockIdx.x * 256 + threadIdx.x;
  if (idx >= S_LEN * 32) return;
  int t = idx >> 5, j = idx & 31;
  double invf = pow(base, -(double)j / 32.0);
  double f = fmod((double)t * invf, 6.283185307179586476925286766559);
  float ff = (float)f;
  cosT[idx] = cosf(ff);
  sinT[idx] = sinf(ff);
}

// ---------------------------------------------------------------- split GEMM (NT)
__global__ __launch_bounds__(256) void gemm_split(
    const unsigned short* __restrict__ Ah, const unsigned short* __restrict__ Al,
    const unsigned short* __restrict__ Bh0, const unsigned short* __restrict__ Bl0,
    const unsigned short* __restrict__ Bh1, const unsigned short* __restrict__ Bl1,
    float* O0, float* O1, int M, int K)
{
  __shared__ unsigned short Ash[128 * 64];
  __shared__ unsigned short Asl[128 * 64];
  __shared__ unsigned short Bsh[128 * 64];
  __shared__ unsigned short Bsl[128 * 64];
  const unsigned short* Bh = blockIdx.z ? Bh1 : Bh0;
  const unsigned short* Bl = blockIdx.z ? Bl1 : Bl0;
  float* O = blockIdx.z ? O1 : O0;
  const int m0 = blockIdx.y * 128, n0 = blockIdx.x * 128;
  const int tid = threadIdx.x, wid = tid >> 6, lane = tid & 63;
  const int lr = lane & 15, lk = (lane >> 4) * 8;
  const int wr = (wid >> 1) * 64, wc = (wid & 1) * 64;
  const int strow = lane >> 3;
  const int stcol = (lane & 7) * 8;

  f32x4 acc[4][4];
#pragma unroll
  for (int m = 0; m < 4; m++)
#pragma unroll
    for (int n = 0; n < 4; n++) acc[m][n] = (f32x4){0.f, 0.f, 0.f, 0.f};

  for (int kt = 0; kt < K; kt += 64) {
#pragma unroll
    for (int i = 0; i < 4; i++) {
      int c = wid * 4 + i;
      int row = c * 8 + strow;
      GLL16(Ah + (size_t)(m0 + row) * K + kt + stcol, &Ash[c * 512]);
      GLL16(Al + (size_t)(m0 + row) * K + kt + stcol, &Asl[c * 512]);
      GLL16(Bh + (size_t)(n0 + row) * K + kt + stcol, &Bsh[c * 512]);
      GLL16(Bl + (size_t)(n0 + row) * K + kt + stcol, &Bsl[c * 512]);
    }
    __syncthreads();
    bf16x8 ah[4][2], al[4][2], bh[4][2], bl[4][2];
#pragma unroll
    for (int m = 0; m < 4; m++)
#pragma unroll
      for (int kk = 0; kk < 2; kk++) {
        ah[m][kk] = *(const bf16x8*)&Ash[(wr + m * 16 + lr) * 64 + kk * 32 + lk];
        al[m][kk] = *(const bf16x8*)&Asl[(wr + m * 16 + lr) * 64 + kk * 32 + lk];
      }
#pragma unroll
    for (int n = 0; n < 4; n++)
#pragma unroll
      for (int kk = 0; kk < 2; kk++) {
        bh[n][kk] = *(const bf16x8*)&Bsh[(wc + n * 16 + lr) * 64 + kk * 32 + lk];
        bl[n][kk] = *(const bf16x8*)&Bsl[(wc + n * 16 + lr) * 64 + kk * 32 + lk];
      }
#pragma unroll
    for (int m = 0; m < 4; m++)
#pragma unroll
      for (int n = 0; n < 4; n++)
#pragma unroll
        for (int kk = 0; kk < 2; kk++) {
          acc[m][n] = __builtin_amdgcn_mfma_f32_16x16x32_bf16(
              al[m][kk], bh[n][kk], acc[m][n], 0, 0, 0);
          acc[m][n] = __builtin_amdgcn_mfma_f32_16x16x32_bf16(
              ah[m][kk], bl[n][kk], acc[m][n], 0, 0, 0);
          acc[m][n] = __builtin_amdgcn_mfma_f32_16x16x32_bf16(
              ah[m][kk], bh[n][kk], acc[m][n], 0, 0, 0);
        }
    __syncthreads();
  }

  const int rbase = m0 + wr + (lane >> 4) * 4;
  const int cbase = n0 + wc + lr;
#pragma unroll
  for (int m = 0; m < 4; m++)
#pragma unroll
    for (int n = 0; n < 4; n++)
#pragma unroll
      for (int j = 0; j < 4; j++) {
        int s = rbase + m * 16 + j;
        int o = cbase + n * 16;
        O[((size_t)(o >> 6) * M + s) * HD + (o & 63)] = acc[m][n][j];
      }
}

// ---------------------------------------------------------------- plain GEMM (NT)
// mode 2: fp32 out row-major [M][N]
// mode 3: fp16 out as V^T in swizzled tile layout
__global__ __launch_bounds__(256) void gemm_nt(
    const unsigned short* __restrict__ A,
    const unsigned short* __restrict__ B0,
    void* O0, int M, int N, int K, int mode)
{
  __shared__ unsigned short As[128 * 64];
  __shared__ unsigned short Bs[128 * 64];
  const unsigned short* B = B0;
  const int m0 = blockIdx.y * 128, n0 = blockIdx.x * 128;
  const int tid = threadIdx.x, wid = tid >> 6, lane = tid & 63;
  const int lr = lane & 15, lk = (lane >> 4) * 8;
  const int wr = (wid >> 1) * 64, wc = (wid & 1) * 64;
  const int strow = lane >> 3;
  const int stcol = (lane & 7) * 8;

  f32x4 acc[4][4];
#pragma unroll
  for (int m = 0; m < 4; m++)
#pragma unroll
    for (int n = 0; n < 4; n++) acc[m][n] = (f32x4){0.f, 0.f, 0.f, 0.f};

  for (int kt = 0; kt < K; kt += 64) {
#pragma unroll
    for (int i = 0; i < 4; i++) {
      int c = wid * 4 + i;
      int row = c * 8 + strow;
      GLL16(A + (size_t)(m0 + row) * K + kt + stcol, &As[c * 512]);
      GLL16(B + (size_t)(n0 + row) * K + kt + stcol, &Bs[c * 512]);
    }
    __syncthreads();
    bf16x8 af[4][2], bfr[4][2];
#pragma unroll
    for (int m = 0; m < 4; m++)
#pragma unroll
      for (int kk = 0; kk < 2; kk++)
        af[m][kk] = *(const bf16x8*)&As[(wr + m * 16 + lr) * 64 + kk * 32 + lk];
#pragma unroll
    for (int n = 0; n < 4; n++)
#pragma unroll
      for (int kk = 0; kk < 2; kk++)
        bfr[n][kk] = *(const bf16x8*)&Bs[(wc + n * 16 + lr) * 64 + kk * 32 + lk];
#pragma unroll
    for (int m = 0; m < 4; m++)
#pragma unroll
      for (int n = 0; n < 4; n++)
#pragma unroll
        for (int kk = 0; kk < 2; kk++)
          acc[m][n] = __builtin_amdgcn_mfma_f32_16x16x32_bf16(
              af[m][kk], bfr[n][kk], acc[m][n], 0, 0, 0);
    __syncthreads();
  }

  const int rbase = m0 + wr + (lane >> 4) * 4;
  const int cbase = n0 + wc + lr;
  if (mode == 3) {
    char* base = (char*)O0;
#pragma unroll
    for (int m = 0; m < 4; m++)
#pragma unroll
      for (int n = 0; n < 4; n++) {
        int s = rbase + m * 16;
        int o = cbase + n * 16;
        int hd = o >> 6, d = o & 63;
        size_t tb = (size_t)hd * PLANE_BYTES + (size_t)(s >> 6) * TILE_BYTES
                  + (size_t)d * 128;
        int cbyte = (2 * (s & 63)) ^ ((d & 7) << 4);
        u16x4 r;
#pragma unroll
        for (int j = 0; j < 4; j++) r[j] = f2h(acc[m][n][j]);
        *(u16x4*)(base + tb + cbyte) = r;
      }
  } else {
    float* C = (float*)O0;
#pragma unroll
    for (int m = 0; m < 4; m++)
#pragma unroll
      for (int n = 0; n < 4; n++)
#pragma unroll
        for (int j = 0; j < 4; j++) {
          int s = rbase + m * 16 + j;
          int o = cbase + n * 16;
          C[(size_t)s * N + o] = acc[m][n][j];
        }
  }
}

// ---------------------------------------------------------------- rope apply
// Q: fp32 [head][s][d] -> Q16 fp16 plane [head][s][d], pre-scaled by 8*log2(e).
// K: fp32 [head][s][d] -> Kt fp16 plane in swizzled tile layout.
__global__ __launch_bounds__(256) void rope_apply(
    const float* __restrict__ Qf, const float* __restrict__ Kf,
    unsigned short* __restrict__ Q16, char* __restrict__ Kt,
    const float* __restrict__ cosT, const float* __restrict__ sinT)
{
  int wid = threadIdx.x >> 6, lane = threadIdx.x & 63;
  int row = blockIdx.x * 4 + wid;          // 0 .. NH*S_LEN-1, [head][s]
  int t = row & (S_LEN - 1);
  int head = row >> 12;
  int j = (lane < 32) ? lane : (lane - 32);
  float c = cosT[t * 32 + j], s = sinT[t * 32 + j];
  int partner = (lane < 32) ? (2 * lane + 1) : (2 * (lane - 32));
  float sgn = (lane < 32) ? -1.0f : 1.0f;
  const float* qp = Qf + (size_t)row * HD;
  const float* kp = Kf + (size_t)row * HD;
  float q = qp[lane], k = kp[lane];
  float qo = __shfl(q, partner, 64);
  float ko = __shfl(k, partner, 64);
  // fold score scale 8 and log2(e) into Q: softmax in exp2 domain
  float qr = (q * c + sgn * qo * s) * 11.541560327111707f;
  float kr = k * c + sgn * ko * s;
  Q16[(size_t)row * HD + lane] = f2h(qr);
  size_t kb = (size_t)head * PLANE_BYTES + (size_t)(t >> 6) * TILE_BYTES
            + (size_t)(t & 63) * 128 + ((2 * lane) ^ ((t & 7) << 4));
  *(unsigned short*)(Kt + kb) = f2h(kr);
}

// ---------------------------------------------------------------- attention
// Swapped-operand flash attention, fp16 32x32 MFMA, exp2-domain softmax.
// Q16 fp16 [head][s][d] (pre-scaled); Kt/Vt fp16 swizzled tile planes.
// grid (32, 16); 4 waves/block; each wave owns 32 q rows (q = qw + (lane&31)).
__global__ __launch_bounds__(256) void attn_kernel(
    const unsigned short* __restrict__ Q16, const char* __restrict__ Kt,
    const char* __restrict__ Vt, unsigned short* __restrict__ Oattn)
{
  __shared__ char KL[2][TILE_BYTES];
  __shared__ char VL[2][TILE_BYTES];

  const int tid = threadIdx.x, wid = tid >> 6, lane = tid & 63;
  const int l5 = lane & 31, hi2 = lane >> 5;
  const bool lohalf = (hi2 == 0);

  // head->XCD swizzle: heads {x, x+8} live on XCD x
  int id = blockIdx.x + 32 * blockIdx.y;
  int h  = (id & 7) + 8 * ((id >> 3) & 1);
  int bx = id >> 4;
  const int qw = bx * 128 + wid * 32;

  const size_t hoff = (size_t)h * PLANE_BYTES;
  const char* KtH = Kt + hoff;
  const char* VtH = Vt + hoff;

  // Q fragments: B-operand, col = q = qw + l5, k-octet d = 16ks + 8hi2 + i
  const unsigned short* Qrow = Q16 + ((size_t)h * S_LEN + qw + l5) * HD;
  f16x8 qf[4];
#pragma unroll
  for (int ks = 0; ks < 4; ks++)
    qf[ks] = *(const f16x8*)&Qrow[ks * 16 + hi2 * 8];

  f32x16 o0 = (f32x16)0.0f, o1 = (f32x16)0.0f;
  float m_q = -__builtin_inff(), l_q = 0.f;

#define STAGE(kt, b) do { \
    size_t tb = (size_t)(kt) * TILE_BYTES; \
    _Pragma("unroll") \
    for (int c = 0; c < 2; c++) { \
      int ub = c * 4096 + wid * 1024; \
      int go = ub + lane * 16; \
      GLL16(KtH + tb + go, &KL[b][ub]); \
      GLL16(VtH + tb + go, &VL[b][ub]); \
    } } while (0)

  STAGE(0, 0);

  const int NT = S_LEN / 64;
  for (int kt = 0; kt < NT; ++kt) {
    const int cur = kt & 1;
    // drain own stage loads for tile kt (issued one full compute phase ago)
    asm volatile("s_waitcnt vmcnt(0)" ::: "memory");
    __builtin_amdgcn_s_barrier();
    asm volatile("" ::: "memory");

    // prefetch next tile into the other buffer (safe: all waves passed the
    // barrier => all finished reading buf[cur^1] at tile kt-1)
    if (kt + 1 < NT) STAGE(kt + 1, cur ^ 1);

    // ---- S^T = K Q : rows kv, cols q ----
    f32x16 s0 = (f32x16)0.0f, s1 = (f32x16)0.0f;
    __builtin_amdgcn_s_setprio(1);
#pragma unroll
    for (int ks = 0; ks < 4; ks++) {
      const int coff = (32 * ks + 16 * hi2) ^ ((l5 & 7) << 4);
      f16x8 k0 = *(const f16x8*)(&KL[cur][l5 * 128 + coff]);
      f16x8 k1 = *(const f16x8*)(&KL[cur][(32 + l5) * 128 + coff]);
      s0 = __builtin_amdgcn_mfma_f32_32x32x16_f16(k0, qf[ks], s0, 0, 0, 0);
      s1 = __builtin_amdgcn_mfma_f32_32x32x16_f16(k1, qf[ks], s1, 0, 0, 0);
    }
    __builtin_amdgcn_s_setprio(0);

    // ---- per-lane online softmax in exp2 domain (q = qw + l5) ----
    float mx = fmaxf(s0[0], s1[0]);
#pragma unroll
    for (int r = 1; r < 16; r++) mx = fmaxf(mx, fmaxf(s0[r], s1[r]));
    mx = fmaxf(mx, permx32(mx));

    // defer-max: only rescale when some lane's max grew past threshold
    if (__any(mx > m_q + 11.0f)) {
      float mnew = fmaxf(m_q, mx);
      float alpha = exp2a(m_q - mnew);
      m_q = mnew;
      l_q *= alpha;
#pragma unroll
      for (int i = 0; i < 16; i++) { o0[i] *= alpha; o1[i] *= alpha; }
    }

    // ---- P = 2^(S-m): fused exp/sum/pack/exchange -> fp16 B-fragments ----
    f16x8 pf[4];
    float rs = 0.f;
#pragma unroll
    for (int ks = 0; ks < 4; ks++) {
      f32x16 sv = (ks < 2) ? s0 : s1;
      const int base = (ks & 1) * 8;
      float e0 = exp2a(sv[base + 0] - m_q);
      float e1 = exp2a(sv[base + 1] - m_q);
      float e2 = exp2a(sv[base + 2] - m_q);
      float e3 = exp2a(sv[base + 3] - m_q);
      float e4 = exp2a(sv[base + 4] - m_q);
      float e5 = exp2a(sv[base + 5] - m_q);
      float e6 = exp2a(sv[base + 6] - m_q);
      float e7 = exp2a(sv[base + 7] - m_q);
      rs += ((e0 + e1) + (e2 + e3)) + ((e4 + e5) + (e6 + e7));
      unsigned a0 = pkh(e0, e1);
      unsigned a1 = pkh(e2, e3);
      unsigned b0 = pkh(e4, e5);
      unsigned b1 = pkh(e6, e7);
      unsigned sw0 = permx32u(lohalf ? b0 : a0);
      unsigned sw1 = permx32u(lohalf ? b1 : a1);
      u32x4 w;
      w[0] = lohalf ? a0 : sw0;
      w[1] = lohalf ? a1 : sw1;
      w[2] = lohalf ? sw0 : b0;
      w[3] = lohalf ? sw1 : b1;
      union { u32x4 u; f16x8 f; } cv; cv.u = w;
      pf[ks] = cv.f;
    }
    rs += permx32(rs);
    l_q += rs;

    // ---- O^T += V^T P : rows d, cols q ----
    __builtin_amdgcn_s_setprio(1);
#pragma unroll
    for (int ks = 0; ks < 4; ks++) {
      const int coff = (32 * ks + 16 * hi2) ^ ((l5 & 7) << 4);
      f16x8 v0 = *(const f16x8*)(&VL[cur][l5 * 128 + coff]);
      f16x8 v1 = *(const f16x8*)(&VL[cur][(32 + l5) * 128 + coff]);
      o0 = __builtin_amdgcn_mfma_f32_32x32x16_f16(v0, pf[ks], o0, 0, 0, 0);
      o1 = __builtin_amdgcn_mfma_f32_32x32x16_f16(v1, pf[ks], o1, 0, 0, 0);
    }
    __builtin_amdgcn_s_setprio(0);
  }
#undef STAGE

  // ---- epilogue: lane holds O^T[d][q=qw+l5], scale 1/l, write bf16 ----
  const float inv = 1.0f / l_q;
  unsigned* orow = (unsigned*)(Oattn + (size_t)(qw + l5) * 1024 + h * HD);
#pragma unroll
  for (int k = 0; k < 8; k++) {
    const int d0 = 2 * (k & 1) + 8 * (k >> 1) + 4 * hi2;
    unsigned w0 = (unsigned)f2bf(o0[2 * k] * inv)
                | ((unsigned)f2bf(o0[2 * k + 1] * inv) << 16);
    unsigned w1 = (unsigned)f2bf(o1[2 * k] * inv)
                | ((unsigned)f2bf(o1[2 * k + 1] * inv) << 16);
    orow[d0 >> 1] = w0;
    orow[(d0 + 32) >> 1] = w1;
  }
}

// ---------------------------------------------------------------- launch
extern "C" void kernel_launch(void* const* d_in, const int* in_sizes, int n_in,
                              void* d_out, int out_size, void* d_ws, size_t ws_size,
                              hipStream_t stream)
{
  const float* hs = (const float*)d_in[0];
  const float* Wq = (const float*)d_in[1];
  const float* Wk = (const float*)d_in[2];
  const float* Wv = (const float*)d_in[3];
  const float* Wo = (const float*)d_in[4];

  char* ws = (char*)d_ws;
  const size_t HS = (size_t)S_LEN * 1024;
  const size_t WN = (size_t)1024 * 1024;
  size_t off = 0;
  unsigned short* hsh = (unsigned short*)(ws + off); off += HS * 2;   // -> Q16
  unsigned short* hsl = (unsigned short*)(ws + off); off += HS * 2;   // -> Kt
  unsigned short* wqh = (unsigned short*)(ws + off); off += WN * 2;   // -> Ab
  unsigned short* wql = (unsigned short*)(ws + off); off += WN * 2;
  unsigned short* wkh = (unsigned short*)(ws + off); off += WN * 2;
  unsigned short* wkl = (unsigned short*)(ws + off); off += WN * 2;
  unsigned short* wvb = (unsigned short*)(ws + off); off += WN * 2;
  unsigned short* wob = (unsigned short*)(ws + off); off += WN * 2;
  float* Qf = (float*)(ws + off); off += HS * 4;
  float* Kf = (float*)(ws + off); off += HS * 4;
  char* VT_g = ws + off; off += (size_t)NH * PLANE_BYTES;
  float* cosT = (float*)(ws + off); off += (size_t)S_LEN * 32 * 4;
  float* sinT = (float*)(ws + off); off += (size_t)S_LEN * 32 * 4;
  // aliases (regions dead by the time they're written):
  unsigned short* Q16 = hsh;   // hsh dead after gemm_split + V-gemm (both before rope)
  char* Kt_g = (char*)hsl;     // hsl dead after gemm_split
  unsigned short* Ab = wqh;    // wqh..wkl (8MB) dead after gemm_split; wob preserved

  cvt_kernel<<<4096, 256, 0, stream>>>(hs, Wq, Wk, Wv, Wo,
                                       hsh, hsl, wqh, wql, wkh, wkl, wvb, wob);

  double base = 10000.0 * pow((double)S_LEN / 2048.0, 64.0 / 62.0);
  rope_table<<<(S_LEN * 32 + 255) / 256, 256, 0, stream>>>(cosT, sinT, base);

  gemm_split<<<dim3(8, 32, 2), 256, 0, stream>>>(
      hsh, hsl, wqh, wql, wkh, wkl, Qf, Kf, S_LEN, 1024);

  gemm_nt<<<dim3(8, 32, 1), 256, 0, stream>>>(
      hsh, wvb, VT_g, S_LEN, 1024, 1024, 3);

  rope_apply<<<NH * S_LEN / 4, 256, 0, stream>>>(
      Qf, Kf, Q16, Kt_g, cosT, sinT);

  attn_kernel<<<dim3(32, 16), 256, 0, stream>>>(
      Q16, Kt_g, VT_g, Ab);

  gemm_nt<<<dim3(8, 32, 1), 256, 0, stream>>>(
      Ab, wob, d_out, S_LEN, 1024, 1024, 2);
}

// Round 6
// 213.163 us; speedup vs baseline: 2.2288x; 1.3356x over previous
//
#include <hip/hip_runtime.h>
#include <cmath>
#include <cstdint>

#define S_LEN 4096
#define NH 16
#define HD 64

typedef _Float16 f16x8 __attribute__((ext_vector_type(8)));
typedef __attribute__((ext_vector_type(4))) float f32x4;
typedef __attribute__((ext_vector_type(16))) float f32x16;
typedef __attribute__((ext_vector_type(4))) unsigned short u16x4;
typedef __attribute__((ext_vector_type(4))) unsigned int u32x4;
typedef __attribute__((ext_vector_type(4))) float f4;

__device__ __forceinline__ unsigned short f2h(float x) {
  union { _Float16 h; unsigned short u; } v; v.h = (_Float16)x; return v.u;
}
__device__ __forceinline__ float permx32(float v) {
  int idx = (((int)(threadIdx.x & 63)) ^ 32) << 2;
  return __int_as_float(__builtin_amdgcn_ds_bpermute(idx, __float_as_int(v)));
}
__device__ __forceinline__ unsigned permx32u(unsigned v) {
  int idx = (((int)(threadIdx.x & 63)) ^ 32) << 2;
  return (unsigned)__builtin_amdgcn_ds_bpermute(idx, (int)v);
}
__device__ __forceinline__ float exp2a(float x) {
  float r; asm("v_exp_f32 %0, %1" : "=v"(r) : "v"(x)); return r;
}
// packs: low16 = f16(a), high16 = f16(b), round-toward-zero
__device__ __forceinline__ unsigned pkh(float a, float b) {
  unsigned r;
  asm("v_cvt_pkrtz_f16_f32 %0, %1, %2" : "=v"(r) : "v"(a), "v"(b));
  return r;
}

#define GLL16(g, l) __builtin_amdgcn_global_load_lds( \
    (const __attribute__((address_space(1))) void*)(g), \
    (__attribute__((address_space(3))) void*)(l), 16, 0, 0)

// per-head byte size of a swizzled-tile plane: 4096 rows * 128B
#define PLANE_BYTES 524288
// one 64x64 2-byte tile: 8KB
#define TILE_BYTES 8192

// ---------------------------------------------------------------- convert
// all five inputs -> fp16 planes
__global__ __launch_bounds__(256) void cvt_kernel(
    const float* __restrict__ hs, const float* __restrict__ wq,
    const float* __restrict__ wk, const float* __restrict__ wv,
    const float* __restrict__ wo,
    unsigned short* __restrict__ hs16,
    unsigned short* __restrict__ wq16, unsigned short* __restrict__ wk16,
    unsigned short* __restrict__ wv16, unsigned short* __restrict__ wo16)
{
  const int HID4 = (S_LEN * 1024) / 4;   // 1048576
  const int W4   = (1024 * 1024) / 4;    // 262144
  const int total = HID4 + 4 * W4;
  for (int i = blockIdx.x * 256 + threadIdx.x; i < total;
       i += gridDim.x * 256) {
    const float* s; unsigned short* d; int off;
    if (i < HID4) { s = hs; d = hs16; off = i; }
    else {
      int j = i - HID4; int w = j >> 18; off = j & (W4 - 1);
      s = (w == 0) ? wq : (w == 1) ? wk : (w == 2) ? wv : wo;
      d = (w == 0) ? wq16 : (w == 1) ? wk16 : (w == 2) ? wv16 : wo16;
    }
    f4 v = *(const f4*)(s + (size_t)off * 4);
    u16x4 r;
#pragma unroll
    for (int j = 0; j < 4; j++) r[j] = f2h(v[j]);
    *(u16x4*)(d + (size_t)off * 4) = r;
  }
}

// ---------------------------------------------------------------- rope table
__global__ __launch_bounds__(256) void rope_table(
    float* __restrict__ cosT, float* __restrict__ sinT, double base)
{
  int idx = blockIdx.x * 256 + threadIdx.x;
  if (idx >= S_LEN * 32) return;
  int t = idx >> 5, j = idx & 31;
  double invf = pow(base, -(double)j / 32.0);
  double f = fmod((double)t * invf, 6.283185307179586476925286766559);
  float ff = (float)f;
  cosT[idx] = cosf(ff);
  sinT[idx] = sinf(ff);
}

// ---------------------------------------------------------------- fp16 GEMM (NT)
// C[M][N] = sum_k A[M][K]*B[N][K]; A,B fp16 row-major.
// fin=0 (QKV): z=0/1 -> fp32 [head][s][d] (Q/K); z=2 -> fp16 V^T swizzled plane.
// fin=1: fp32 out row-major [M][1024].
__global__ __launch_bounds__(256) void gemm_f16(
    const unsigned short* __restrict__ A,
    const unsigned short* __restrict__ B0, const unsigned short* __restrict__ B1,
    const unsigned short* __restrict__ B2,
    void* O0, void* O1, void* O2, int M, int K, int fin)
{
  __shared__ unsigned short As[128 * 64];
  __shared__ unsigned short Bs[128 * 64];
  const int z = blockIdx.z;
  const unsigned short* B = (z == 0) ? B0 : (z == 1) ? B1 : B2;
  void* O = (z == 0) ? O0 : (z == 1) ? O1 : O2;
  const int m0 = blockIdx.y * 128, n0 = blockIdx.x * 128;
  const int tid = threadIdx.x, wid = tid >> 6, lane = tid & 63;
  const int lr = lane & 15, lk = (lane >> 4) * 8;
  const int wr = (wid >> 1) * 64, wc = (wid & 1) * 64;
  const int strow = lane >> 3;
  const int stcol = (lane & 7) * 8;

  f32x4 acc[4][4];
#pragma unroll
  for (int m = 0; m < 4; m++)
#pragma unroll
    for (int n = 0; n < 4; n++) acc[m][n] = (f32x4){0.f, 0.f, 0.f, 0.f};

  for (int kt = 0; kt < K; kt += 64) {
#pragma unroll
    for (int i = 0; i < 4; i++) {
      int c = wid * 4 + i;
      int row = c * 8 + strow;
      GLL16(A + (size_t)(m0 + row) * K + kt + stcol, &As[c * 512]);
      GLL16(B + (size_t)(n0 + row) * K + kt + stcol, &Bs[c * 512]);
    }
    __syncthreads();
    f16x8 af[4][2], bfr[4][2];
#pragma unroll
    for (int m = 0; m < 4; m++)
#pragma unroll
      for (int kk = 0; kk < 2; kk++)
        af[m][kk] = *(const f16x8*)&As[(wr + m * 16 + lr) * 64 + kk * 32 + lk];
#pragma unroll
    for (int n = 0; n < 4; n++)
#pragma unroll
      for (int kk = 0; kk < 2; kk++)
        bfr[n][kk] = *(const f16x8*)&Bs[(wc + n * 16 + lr) * 64 + kk * 32 + lk];
#pragma unroll
    for (int m = 0; m < 4; m++)
#pragma unroll
      for (int n = 0; n < 4; n++)
#pragma unroll
        for (int kk = 0; kk < 2; kk++)
          acc[m][n] = __builtin_amdgcn_mfma_f32_16x16x32_f16(
              af[m][kk], bfr[n][kk], acc[m][n], 0, 0, 0);
    __syncthreads();
  }

  const int rbase = m0 + wr + (lane >> 4) * 4;
  const int cbase = n0 + wc + lr;
  if (fin) {
    float* C = (float*)O;
#pragma unroll
    for (int m = 0; m < 4; m++)
#pragma unroll
      for (int n = 0; n < 4; n++)
#pragma unroll
        for (int j = 0; j < 4; j++) {
          int s = rbase + m * 16 + j;
          int o = cbase + n * 16;
          C[(size_t)s * 1024 + o] = acc[m][n][j];
        }
  } else if (z == 2) {
    // V^T swizzled plane, fp16
    char* base = (char*)O;
#pragma unroll
    for (int m = 0; m < 4; m++)
#pragma unroll
      for (int n = 0; n < 4; n++) {
        int s = rbase + m * 16;            // s..s+3, s % 4 == 0
        int o = cbase + n * 16;
        int hd = o >> 6, d = o & 63;
        size_t tb = (size_t)hd * PLANE_BYTES + (size_t)(s >> 6) * TILE_BYTES
                  + (size_t)d * 128;
        int cbyte = (2 * (s & 63)) ^ ((d & 7) << 4);
        u16x4 r;
#pragma unroll
        for (int j = 0; j < 4; j++) r[j] = f2h(acc[m][n][j]);
        *(u16x4*)(base + tb + cbyte) = r;
      }
  } else {
    // Q/K: fp32 [head][s][d]
    float* C = (float*)O;
#pragma unroll
    for (int m = 0; m < 4; m++)
#pragma unroll
      for (int n = 0; n < 4; n++)
#pragma unroll
        for (int j = 0; j < 4; j++) {
          int s = rbase + m * 16 + j;
          int o = cbase + n * 16;
          C[((size_t)(o >> 6) * M + s) * HD + (o & 63)] = acc[m][n][j];
        }
  }
}

// ---------------------------------------------------------------- rope apply
// Q: fp32 [head][s][d] -> Q16 fp16 plane [head][s][d], pre-scaled by 8*log2(e).
// K: fp32 [head][s][d] -> Kt fp16 plane in swizzled tile layout.
__global__ __launch_bounds__(256) void rope_apply(
    const float* __restrict__ Qf, const float* __restrict__ Kf,
    unsigned short* __restrict__ Q16, char* __restrict__ Kt,
    const float* __restrict__ cosT, const float* __restrict__ sinT)
{
  int wid = threadIdx.x >> 6, lane = threadIdx.x & 63;
  int row = blockIdx.x * 4 + wid;          // 0 .. NH*S_LEN-1, [head][s]
  int t = row & (S_LEN - 1);
  int head = row >> 12;
  int j = (lane < 32) ? lane : (lane - 32);
  float c = cosT[t * 32 + j], s = sinT[t * 32 + j];
  int partner = (lane < 32) ? (2 * lane + 1) : (2 * (lane - 32));
  float sgn = (lane < 32) ? -1.0f : 1.0f;
  const float* qp = Qf + (size_t)row * HD;
  const float* kp = Kf + (size_t)row * HD;
  float q = qp[lane], k = kp[lane];
  float qo = __shfl(q, partner, 64);
  float ko = __shfl(k, partner, 64);
  // fold score scale 8 and log2(e) into Q: softmax in exp2 domain
  float qr = (q * c + sgn * qo * s) * 11.541560327111707f;
  float kr = k * c + sgn * ko * s;
  Q16[(size_t)row * HD + lane] = f2h(qr);
  size_t kb = (size_t)head * PLANE_BYTES + (size_t)(t >> 6) * TILE_BYTES
            + (size_t)(t & 63) * 128 + ((2 * lane) ^ ((t & 7) << 4));
  *(unsigned short*)(Kt + kb) = f2h(kr);
}

// ---------------------------------------------------------------- attention
// Swapped-operand flash attention, fp16 32x32 MFMA, exp2-domain softmax.
// Q16 fp16 [head][s][d] (pre-scaled); Kt/Vt fp16 swizzled tile planes.
// grid (32, 16); 4 waves/block; each wave owns 32 q rows (q = qw + (lane&31)).
// min-waves-per-EU = 2: occupancy is structurally 2 waves/SIMD (2048 waves
// total), so give the register allocator the full 256-VGPR budget to keep
// both f32x16 accumulator pairs out of AGPRs (no accvgpr_read/write traffic).
__global__ __launch_bounds__(256, 2) void attn_kernel(
    const unsigned short* __restrict__ Q16, const char* __restrict__ Kt,
    const char* __restrict__ Vt, unsigned short* __restrict__ Oattn)
{
  __shared__ char KL[2][TILE_BYTES];
  __shared__ char VL[2][TILE_BYTES];

  const int tid = threadIdx.x, wid = tid >> 6, lane = tid & 63;
  const int l5 = lane & 31, hi2 = lane >> 5;
  const bool lohalf = (hi2 == 0);

  // head->XCD swizzle: heads {x, x+8} live on XCD x
  int id = blockIdx.x + 32 * blockIdx.y;
  int h  = (id & 7) + 8 * ((id >> 3) & 1);
  int bx = id >> 4;
  const int qw = bx * 128 + wid * 32;

  const size_t hoff = (size_t)h * PLANE_BYTES;
  const char* KtH = Kt + hoff;
  const char* VtH = Vt + hoff;

  // Q fragments: B-operand, col = q = qw + l5, k-octet d = 16ks + 8hi2 + i
  const unsigned short* Qrow = Q16 + ((size_t)h * S_LEN + qw + l5) * HD;
  f16x8 qf[4];
#pragma unroll
  for (int ks = 0; ks < 4; ks++)
    qf[ks] = *(const f16x8*)&Qrow[ks * 16 + hi2 * 8];

  f32x16 o0 = (f32x16)0.0f, o1 = (f32x16)0.0f;
  float m_q = -__builtin_inff(), l_q = 0.f;

#define STAGE(kt, b) do { \
    size_t tb = (size_t)(kt) * TILE_BYTES; \
    _Pragma("unroll") \
    for (int c = 0; c < 2; c++) { \
      int ub = c * 4096 + wid * 1024; \
      int go = ub + lane * 16; \
      GLL16(KtH + tb + go, &KL[b][ub]); \
      GLL16(VtH + tb + go, &VL[b][ub]); \
    } } while (0)

  STAGE(0, 0);

  const int NT = S_LEN / 64;
  for (int kt = 0; kt < NT; ++kt) {
    const int cur = kt & 1;
    // drain own stage loads for tile kt (issued one full compute phase ago)
    asm volatile("s_waitcnt vmcnt(0)" ::: "memory");
    __builtin_amdgcn_s_barrier();
    asm volatile("" ::: "memory");

    // prefetch next tile into the other buffer (safe: all waves passed the
    // barrier => all finished reading buf[cur^1] at tile kt-1)
    if (kt + 1 < NT) STAGE(kt + 1, cur ^ 1);

    // ---- S^T = K Q : rows kv, cols q ----
    f32x16 s0 = (f32x16)0.0f, s1 = (f32x16)0.0f;
    __builtin_amdgcn_s_setprio(1);
#pragma unroll
    for (int ks = 0; ks < 4; ks++) {
      const int coff = (32 * ks + 16 * hi2) ^ ((l5 & 7) << 4);
      f16x8 k0 = *(const f16x8*)(&KL[cur][l5 * 128 + coff]);
      f16x8 k1 = *(const f16x8*)(&KL[cur][(32 + l5) * 128 + coff]);
      s0 = __builtin_amdgcn_mfma_f32_32x32x16_f16(k0, qf[ks], s0, 0, 0, 0);
      s1 = __builtin_amdgcn_mfma_f32_32x32x16_f16(k1, qf[ks], s1, 0, 0, 0);
    }
    __builtin_amdgcn_s_setprio(0);

    // ---- per-lane online softmax in exp2 domain (q = qw + l5) ----
    float mx = fmaxf(s0[0], s1[0]);
#pragma unroll
    for (int r = 1; r < 16; r++) mx = fmaxf(mx, fmaxf(s0[r], s1[r]));
    mx = fmaxf(mx, permx32(mx));

    // defer-max: only rescale when some lane's max grew past threshold
    if (__any(mx > m_q + 11.0f)) {
      float mnew = fmaxf(m_q, mx);
      float alpha = exp2a(m_q - mnew);
      m_q = mnew;
      l_q *= alpha;
#pragma unroll
      for (int i = 0; i < 16; i++) { o0[i] *= alpha; o1[i] *= alpha; }
    }

    // ---- P = 2^(S-m): fused exp/sum/pack/exchange -> fp16 B-fragments ----
    f16x8 pf[4];
    float rs = 0.f;
#pragma unroll
    for (int ks = 0; ks < 4; ks++) {
      f32x16 sv = (ks < 2) ? s0 : s1;
      const int base = (ks & 1) * 8;
      float e0 = exp2a(sv[base + 0] - m_q);
      float e1 = exp2a(sv[base + 1] - m_q);
      float e2 = exp2a(sv[base + 2] - m_q);
      float e3 = exp2a(sv[base + 3] - m_q);
      float e4 = exp2a(sv[base + 4] - m_q);
      float e5 = exp2a(sv[base + 5] - m_q);
      float e6 = exp2a(sv[base + 6] - m_q);
      float e7 = exp2a(sv[base + 7] - m_q);
      rs += ((e0 + e1) + (e2 + e3)) + ((e4 + e5) + (e6 + e7));
      unsigned a0 = pkh(e0, e1);
      unsigned a1 = pkh(e2, e3);
      unsigned b0 = pkh(e4, e5);
      unsigned b1 = pkh(e6, e7);
      unsigned sw0 = permx32u(lohalf ? b0 : a0);
      unsigned sw1 = permx32u(lohalf ? b1 : a1);
      u32x4 w;
      w[0] = lohalf ? a0 : sw0;
      w[1] = lohalf ? a1 : sw1;
      w[2] = lohalf ? sw0 : b0;
      w[3] = lohalf ? sw1 : b1;
      union { u32x4 u; f16x8 f; } cv; cv.u = w;
      pf[ks] = cv.f;
    }
    rs += permx32(rs);
    l_q += rs;

    // ---- O^T += V^T P : rows d, cols q ----
    __builtin_amdgcn_s_setprio(1);
#pragma unroll
    for (int ks = 0; ks < 4; ks++) {
      const int coff = (32 * ks + 16 * hi2) ^ ((l5 & 7) << 4);
      f16x8 v0 = *(const f16x8*)(&VL[cur][l5 * 128 + coff]);
      f16x8 v1 = *(const f16x8*)(&VL[cur][(32 + l5) * 128 + coff]);
      o0 = __builtin_amdgcn_mfma_f32_32x32x16_f16(v0, pf[ks], o0, 0, 0, 0);
      o1 = __builtin_amdgcn_mfma_f32_32x32x16_f16(v1, pf[ks], o1, 0, 0, 0);
    }
    __builtin_amdgcn_s_setprio(0);
  }
#undef STAGE

  // ---- epilogue: lane holds O^T[d][q=qw+l5], scale 1/l, write fp16 ----
  const float inv = 1.0f / l_q;
  unsigned* orow = (unsigned*)(Oattn + (size_t)(qw + l5) * 1024 + h * HD);
#pragma unroll
  for (int k = 0; k < 8; k++) {
    const int d0 = 2 * (k & 1) + 8 * (k >> 1) + 4 * hi2;
    orow[d0 >> 1]        = pkh(o0[2 * k] * inv, o0[2 * k + 1] * inv);
    orow[(d0 + 32) >> 1] = pkh(o1[2 * k] * inv, o1[2 * k + 1] * inv);
  }
}

// ---------------------------------------------------------------- launch
extern "C" void kernel_launch(void* const* d_in, const int* in_sizes, int n_in,
                              void* d_out, int out_size, void* d_ws, size_t ws_size,
                              hipStream_t stream)
{
  const float* hs = (const float*)d_in[0];
  const float* Wq = (const float*)d_in[1];
  const float* Wk = (const float*)d_in[2];
  const float* Wv = (const float*)d_in[3];
  const float* Wo = (const float*)d_in[4];

  char* ws = (char*)d_ws;
  const size_t HS = (size_t)S_LEN * 1024;      // 4194304 elems
  const size_t WN = (size_t)1024 * 1024;
  size_t off = 0;
  unsigned short* hs16 = (unsigned short*)(ws + off); off += HS * 2;   // 8MB -> Q16
  unsigned short* wq16 = (unsigned short*)(ws + off); off += WN * 2;
  unsigned short* wk16 = (unsigned short*)(ws + off); off += WN * 2;
  unsigned short* wv16 = (unsigned short*)(ws + off); off += WN * 2;
  unsigned short* wo16 = (unsigned short*)(ws + off); off += WN * 2;
  float* Qf = (float*)(ws + off); off += HS * 4;                       // 16MB -> Ab
  float* Kf = (float*)(ws + off); off += HS * 4;                       // 16MB
  char* VT_g = ws + off; off += (size_t)NH * PLANE_BYTES;              // 8MB
  char* Kt_g = ws + off; off += (size_t)NH * PLANE_BYTES;              // 8MB
  float* cosT = (float*)(ws + off); off += (size_t)S_LEN * 32 * 4;
  float* sinT = (float*)(ws + off); off += (size_t)S_LEN * 32 * 4;
  // aliases (regions dead by the time they're written):
  unsigned short* Q16 = hs16;   // hs16 dead after gemm_f16 QKV pass
  unsigned short* Ab  = (unsigned short*)Qf;  // Qf dead after rope_apply

  cvt_kernel<<<4096, 256, 0, stream>>>(hs, Wq, Wk, Wv, Wo,
                                       hs16, wq16, wk16, wv16, wo16);

  double base = 10000.0 * pow((double)S_LEN / 2048.0, 64.0 / 62.0);
  rope_table<<<(S_LEN * 32 + 255) / 256, 256, 0, stream>>>(cosT, sinT, base);

  gemm_f16<<<dim3(8, 32, 3), 256, 0, stream>>>(
      hs16, wq16, wk16, wv16, Qf, Kf, VT_g, S_LEN, 1024, 0);

  rope_apply<<<NH * S_LEN / 4, 256, 0, stream>>>(
      Qf, Kf, Q16, Kt_g, cosT, sinT);

  attn_kernel<<<dim3(32, 16), 256, 0, stream>>>(
      Q16, Kt_g, VT_g, Ab);

  gemm_f16<<<dim3(8, 32, 1), 256, 0, stream>>>(
      Ab, wo16, wo16, wo16, d_out, d_out, d_out, S_LEN, 1024, 1);
}

// Round 7
// 209.383 us; speedup vs baseline: 2.2691x; 1.0181x over previous
//
#include <hip/hip_runtime.h>
#include <cmath>
#include <cstdint>

#define S_LEN 4096
#define NH 16
#define HD 64

typedef _Float16 f16x8 __attribute__((ext_vector_type(8)));
typedef __attribute__((ext_vector_type(4))) float f32x4;
typedef __attribute__((ext_vector_type(16))) float f32x16;
typedef __attribute__((ext_vector_type(4))) unsigned short u16x4;
typedef __attribute__((ext_vector_type(4))) unsigned int u32x4;
typedef __attribute__((ext_vector_type(4))) float f4;

__device__ __forceinline__ unsigned short f2h(float x) {
  union { _Float16 h; unsigned short u; } v; v.h = (_Float16)x; return v.u;
}
__device__ __forceinline__ float h2f(unsigned short u) {
  union { unsigned short u; _Float16 h; } v; v.u = u; return (float)v.h;
}
__device__ __forceinline__ float permx32(float v) {
  int idx = (((int)(threadIdx.x & 63)) ^ 32) << 2;
  return __int_as_float(__builtin_amdgcn_ds_bpermute(idx, __float_as_int(v)));
}
__device__ __forceinline__ unsigned permx32u(unsigned v) {
  int idx = (((int)(threadIdx.x & 63)) ^ 32) << 2;
  return (unsigned)__builtin_amdgcn_ds_bpermute(idx, (int)v);
}
__device__ __forceinline__ float exp2a(float x) {
  float r; asm("v_exp_f32 %0, %1" : "=v"(r) : "v"(x)); return r;
}
// packs: low16 = f16(a), high16 = f16(b), round-toward-zero
__device__ __forceinline__ unsigned pkh(float a, float b) {
  unsigned r;
  asm("v_cvt_pkrtz_f16_f32 %0, %1, %2" : "=v"(r) : "v"(a), "v"(b));
  return r;
}

#define GLL16(g, l) __builtin_amdgcn_global_load_lds( \
    (const __attribute__((address_space(1))) void*)(g), \
    (__attribute__((address_space(3))) void*)(l), 16, 0, 0)

// per-head byte size of a swizzled-tile plane: 4096 rows * 128B
#define PLANE_BYTES 524288
// one 64x64 2-byte tile: 8KB
#define TILE_BYTES 8192

// ---------------------------------------------------------------- convert
__global__ __launch_bounds__(256) void cvt_kernel(
    const float* __restrict__ hs, const float* __restrict__ wq,
    const float* __restrict__ wk, const float* __restrict__ wv,
    const float* __restrict__ wo,
    unsigned short* __restrict__ hs16,
    unsigned short* __restrict__ wq16, unsigned short* __restrict__ wk16,
    unsigned short* __restrict__ wv16, unsigned short* __restrict__ wo16)
{
  const int HID4 = (S_LEN * 1024) / 4;
  const int W4   = (1024 * 1024) / 4;
  const int total = HID4 + 4 * W4;
  for (int i = blockIdx.x * 256 + threadIdx.x; i < total;
       i += gridDim.x * 256) {
    const float* s; unsigned short* d; int off;
    if (i < HID4) { s = hs; d = hs16; off = i; }
    else {
      int j = i - HID4; int w = j >> 18; off = j & (W4 - 1);
      s = (w == 0) ? wq : (w == 1) ? wk : (w == 2) ? wv : wo;
      d = (w == 0) ? wq16 : (w == 1) ? wk16 : (w == 2) ? wv16 : wo16;
    }
    f4 v = *(const f4*)(s + (size_t)off * 4);
    u16x4 r;
#pragma unroll
    for (int j = 0; j < 4; j++) r[j] = f2h(v[j]);
    *(u16x4*)(d + (size_t)off * 4) = r;
  }
}

// ---------------------------------------------------------------- rope table
__global__ __launch_bounds__(256) void rope_table(
    float* __restrict__ cosT, float* __restrict__ sinT, double base)
{
  int idx = blockIdx.x * 256 + threadIdx.x;
  if (idx >= S_LEN * 32) return;
  int t = idx >> 5, j = idx & 31;
  double invf = pow(base, -(double)j / 32.0);
  double f = fmod((double)t * invf, 6.283185307179586476925286766559);
  float ff = (float)f;
  cosT[idx] = cosf(ff);
  sinT[idx] = sinf(ff);
}

// ---------------------------------------------------------------- fp16 GEMM (NT)
// C[M][N] = sum_k A[M][K]*B[N][K]; A,B fp16 row-major.
// fin=0 (QKV): z=0/1 -> fp16 [head][s][d] (Q/K); z=2 -> fp16 V^T swizzled plane.
// fin=1: fp32 out row-major [M][1024].
__global__ __launch_bounds__(256) void gemm_f16(
    const unsigned short* __restrict__ A,
    const unsigned short* __restrict__ B0, const unsigned short* __restrict__ B1,
    const unsigned short* __restrict__ B2,
    void* O0, void* O1, void* O2, int M, int K, int fin)
{
  __shared__ unsigned short As[128 * 64];
  __shared__ unsigned short Bs[128 * 64];
  const int z = blockIdx.z;
  const unsigned short* B = (z == 0) ? B0 : (z == 1) ? B1 : B2;
  void* O = (z == 0) ? O0 : (z == 1) ? O1 : O2;
  const int m0 = blockIdx.y * 128, n0 = blockIdx.x * 128;
  const int tid = threadIdx.x, wid = tid >> 6, lane = tid & 63;
  const int lr = lane & 15, lk = (lane >> 4) * 8;
  const int wr = (wid >> 1) * 64, wc = (wid & 1) * 64;
  const int strow = lane >> 3;
  const int stcol = (lane & 7) * 8;

  f32x4 acc[4][4];
#pragma unroll
  for (int m = 0; m < 4; m++)
#pragma unroll
    for (int n = 0; n < 4; n++) acc[m][n] = (f32x4){0.f, 0.f, 0.f, 0.f};

  for (int kt = 0; kt < K; kt += 64) {
#pragma unroll
    for (int i = 0; i < 4; i++) {
      int c = wid * 4 + i;
      int row = c * 8 + strow;
      GLL16(A + (size_t)(m0 + row) * K + kt + stcol, &As[c * 512]);
      GLL16(B + (size_t)(n0 + row) * K + kt + stcol, &Bs[c * 512]);
    }
    __syncthreads();
    f16x8 af[4][2], bfr[4][2];
#pragma unroll
    for (int m = 0; m < 4; m++)
#pragma unroll
      for (int kk = 0; kk < 2; kk++)
        af[m][kk] = *(const f16x8*)&As[(wr + m * 16 + lr) * 64 + kk * 32 + lk];
#pragma unroll
    for (int n = 0; n < 4; n++)
#pragma unroll
      for (int kk = 0; kk < 2; kk++)
        bfr[n][kk] = *(const f16x8*)&Bs[(wc + n * 16 + lr) * 64 + kk * 32 + lk];
#pragma unroll
    for (int m = 0; m < 4; m++)
#pragma unroll
      for (int n = 0; n < 4; n++)
#pragma unroll
        for (int kk = 0; kk < 2; kk++)
          acc[m][n] = __builtin_amdgcn_mfma_f32_16x16x32_f16(
              af[m][kk], bfr[n][kk], acc[m][n], 0, 0, 0);
    __syncthreads();
  }

  const int rbase = m0 + wr + (lane >> 4) * 4;
  const int cbase = n0 + wc + lr;
  if (fin) {
    float* C = (float*)O;
#pragma unroll
    for (int m = 0; m < 4; m++)
#pragma unroll
      for (int n = 0; n < 4; n++)
#pragma unroll
        for (int j = 0; j < 4; j++) {
          int s = rbase + m * 16 + j;
          int o = cbase + n * 16;
          C[(size_t)s * 1024 + o] = acc[m][n][j];
        }
  } else if (z == 2) {
    // V^T swizzled plane, fp16
    char* base = (char*)O;
#pragma unroll
    for (int m = 0; m < 4; m++)
#pragma unroll
      for (int n = 0; n < 4; n++) {
        int s = rbase + m * 16;            // s..s+3, s % 4 == 0
        int o = cbase + n * 16;
        int hd = o >> 6, d = o & 63;
        size_t tb = (size_t)hd * PLANE_BYTES + (size_t)(s >> 6) * TILE_BYTES
                  + (size_t)d * 128;
        int cbyte = (2 * (s & 63)) ^ ((d & 7) << 4);
        u16x4 r;
#pragma unroll
        for (int j = 0; j < 4; j++) r[j] = f2h(acc[m][n][j]);
        *(u16x4*)(base + tb + cbyte) = r;
      }
  } else {
    // Q/K: fp16 [head][s][d]
    unsigned short* C = (unsigned short*)O;
#pragma unroll
    for (int m = 0; m < 4; m++)
#pragma unroll
      for (int n = 0; n < 4; n++)
#pragma unroll
        for (int j = 0; j < 4; j++) {
          int s = rbase + m * 16 + j;
          int o = cbase + n * 16;
          C[((size_t)(o >> 6) * M + s) * HD + (o & 63)] = f2h(acc[m][n][j]);
        }
  }
}

// ---------------------------------------------------------------- rope apply
// Qh/Kh fp16 [head][s][d] -> Q16 fp16 (pre-scaled 8*log2e) + Kt swizzled plane.
__global__ __launch_bounds__(256) void rope_apply(
    const unsigned short* __restrict__ Qh, const unsigned short* __restrict__ Kh,
    unsigned short* __restrict__ Q16, char* __restrict__ Kt,
    const float* __restrict__ cosT, const float* __restrict__ sinT)
{
  int wid = threadIdx.x >> 6, lane = threadIdx.x & 63;
  int row = blockIdx.x * 4 + wid;          // 0 .. NH*S_LEN-1, [head][s]
  int t = row & (S_LEN - 1);
  int head = row >> 12;
  int j = (lane < 32) ? lane : (lane - 32);
  float c = cosT[t * 32 + j], s = sinT[t * 32 + j];
  int partner = (lane < 32) ? (2 * lane + 1) : (2 * (lane - 32));
  float sgn = (lane < 32) ? -1.0f : 1.0f;
  float q = h2f(Qh[(size_t)row * HD + lane]);
  float k = h2f(Kh[(size_t)row * HD + lane]);
  float qo = __shfl(q, partner, 64);
  float ko = __shfl(k, partner, 64);
  // fold score scale 8 and log2(e) into Q: softmax in exp2 domain
  float qr = (q * c + sgn * qo * s) * 11.541560327111707f;
  float kr = k * c + sgn * ko * s;
  Q16[(size_t)row * HD + lane] = f2h(qr);
  size_t kb = (size_t)head * PLANE_BYTES + (size_t)(t >> 6) * TILE_BYTES
            + (size_t)(t & 63) * 128 + ((2 * lane) ^ ((t & 7) << 4));
  *(unsigned short*)(Kt + kb) = f2h(kr);
}

// ---------------------------------------------------------------- attention
// Swapped-operand flash attention, fp16 32x32 MFMA, exp2-domain softmax,
// KV-split 2 for occupancy (4 waves/SIMD).
// grid (32, 16, 2); 4 waves/block; each wave owns 32 q rows (q = qw + lane&31),
// covers KV range [z*2048, (z+1)*2048).
// Outputs: Opart[z][h][s][d] fp16 (normalized partial), Ml[z][h][s]=(m,l) f32.
__global__ __launch_bounds__(256, 4) void attn_kernel(
    const unsigned short* __restrict__ Q16, const char* __restrict__ Kt,
    const char* __restrict__ Vt,
    unsigned short* __restrict__ Opart, float* __restrict__ Ml)
{
  __shared__ char KL[2][TILE_BYTES];
  __shared__ char VL[2][TILE_BYTES];

  const int tid = threadIdx.x, wid = tid >> 6, lane = tid & 63;
  const int l5 = lane & 31, hi2 = lane >> 5;
  const bool lohalf = (hi2 == 0);
  const int z = blockIdx.z;

  // head->XCD swizzle: heads {x, x+8} live on XCD x
  int id = blockIdx.x + 32 * blockIdx.y;
  int h  = (id & 7) + 8 * ((id >> 3) & 1);
  int bx = id >> 4;
  const int qw = bx * 128 + wid * 32;

  const size_t hoff = (size_t)h * PLANE_BYTES;
  const char* KtH = Kt + hoff;
  const char* VtH = Vt + hoff;

  // Q fragments: B-operand, col = q = qw + l5, k-octet d = 16ks + 8hi2 + i
  const unsigned short* Qrow = Q16 + ((size_t)h * S_LEN + qw + l5) * HD;
  f16x8 qf[4];
#pragma unroll
  for (int ks = 0; ks < 4; ks++)
    qf[ks] = *(const f16x8*)&Qrow[ks * 16 + hi2 * 8];

  f32x16 o0 = (f32x16)0.0f, o1 = (f32x16)0.0f;
  float m_q = -__builtin_inff(), l_q = 0.f;

  const int T0 = z * 32;            // first tile of this split
  const int NT = 32;                // tiles per split

#define STAGE(kt, b) do { \
    size_t tb = (size_t)(T0 + (kt)) * TILE_BYTES; \
    _Pragma("unroll") \
    for (int c = 0; c < 2; c++) { \
      int ub = c * 4096 + wid * 1024; \
      int go = ub + lane * 16; \
      GLL16(KtH + tb + go, &KL[b][ub]); \
      GLL16(VtH + tb + go, &VL[b][ub]); \
    } } while (0)

  STAGE(0, 0);

  for (int kt = 0; kt < NT; ++kt) {
    const int cur = kt & 1;
    // drain own stage loads for tile kt (issued one full compute phase ago)
    asm volatile("s_waitcnt vmcnt(0)" ::: "memory");
    __builtin_amdgcn_s_barrier();
    asm volatile("" ::: "memory");

    // prefetch next tile into the other buffer (safe: all waves passed the
    // barrier => all finished reading buf[cur^1] at tile kt-1)
    if (kt + 1 < NT) STAGE(kt + 1, cur ^ 1);

    // ---- S^T = K Q : rows kv, cols q ----
    f32x16 s0 = (f32x16)0.0f, s1 = (f32x16)0.0f;
    __builtin_amdgcn_s_setprio(1);
#pragma unroll
    for (int ks = 0; ks < 4; ks++) {
      const int coff = (32 * ks + 16 * hi2) ^ ((l5 & 7) << 4);
      f16x8 k0 = *(const f16x8*)(&KL[cur][l5 * 128 + coff]);
      f16x8 k1 = *(const f16x8*)(&KL[cur][(32 + l5) * 128 + coff]);
      s0 = __builtin_amdgcn_mfma_f32_32x32x16_f16(k0, qf[ks], s0, 0, 0, 0);
      s1 = __builtin_amdgcn_mfma_f32_32x32x16_f16(k1, qf[ks], s1, 0, 0, 0);
    }
    __builtin_amdgcn_s_setprio(0);

    // ---- per-lane online softmax in exp2 domain (q = qw + l5) ----
    float mx = fmaxf(s0[0], s1[0]);
#pragma unroll
    for (int r = 1; r < 16; r++) mx = fmaxf(mx, fmaxf(s0[r], s1[r]));
    mx = fmaxf(mx, permx32(mx));

    // defer-max: only rescale when some lane's max grew past threshold
    if (__any(mx > m_q + 11.0f)) {
      float mnew = fmaxf(m_q, mx);
      float alpha = exp2a(m_q - mnew);
      m_q = mnew;
      l_q *= alpha;
#pragma unroll
      for (int i = 0; i < 16; i++) { o0[i] *= alpha; o1[i] *= alpha; }
    }

    // ---- P = 2^(S-m): fused exp/sum/pack/exchange -> fp16 B-fragments ----
    f16x8 pf[4];
    float rs = 0.f;
#pragma unroll
    for (int ks = 0; ks < 4; ks++) {
      f32x16 sv = (ks < 2) ? s0 : s1;
      const int base = (ks & 1) * 8;
      float e0 = exp2a(sv[base + 0] - m_q);
      float e1 = exp2a(sv[base + 1] - m_q);
      float e2 = exp2a(sv[base + 2] - m_q);
      float e3 = exp2a(sv[base + 3] - m_q);
      float e4 = exp2a(sv[base + 4] - m_q);
      float e5 = exp2a(sv[base + 5] - m_q);
      float e6 = exp2a(sv[base + 6] - m_q);
      float e7 = exp2a(sv[base + 7] - m_q);
      rs += ((e0 + e1) + (e2 + e3)) + ((e4 + e5) + (e6 + e7));
      unsigned a0 = pkh(e0, e1);
      unsigned a1 = pkh(e2, e3);
      unsigned b0 = pkh(e4, e5);
      unsigned b1 = pkh(e6, e7);
      unsigned sw0 = permx32u(lohalf ? b0 : a0);
      unsigned sw1 = permx32u(lohalf ? b1 : a1);
      u32x4 w;
      w[0] = lohalf ? a0 : sw0;
      w[1] = lohalf ? a1 : sw1;
      w[2] = lohalf ? sw0 : b0;
      w[3] = lohalf ? sw1 : b1;
      union { u32x4 u; f16x8 f; } cv; cv.u = w;
      pf[ks] = cv.f;
    }
    rs += permx32(rs);
    l_q += rs;

    // ---- O^T += V^T P : rows d, cols q ----
    __builtin_amdgcn_s_setprio(1);
#pragma unroll
    for (int ks = 0; ks < 4; ks++) {
      const int coff = (32 * ks + 16 * hi2) ^ ((l5 & 7) << 4);
      f16x8 v0 = *(const f16x8*)(&VL[cur][l5 * 128 + coff]);
      f16x8 v1 = *(const f16x8*)(&VL[cur][(32 + l5) * 128 + coff]);
      o0 = __builtin_amdgcn_mfma_f32_32x32x16_f16(v0, pf[ks], o0, 0, 0, 0);
      o1 = __builtin_amdgcn_mfma_f32_32x32x16_f16(v1, pf[ks], o1, 0, 0, 0);
    }
    __builtin_amdgcn_s_setprio(0);
  }
#undef STAGE

  // ---- epilogue: normalized partial fp16 + (m,l) ----
  const float inv = 1.0f / l_q;
  const int q = qw + l5;
  unsigned* orow = (unsigned*)(Opart + (((size_t)(z * NH + h)) * S_LEN + q) * HD);
#pragma unroll
  for (int k = 0; k < 8; k++) {
    const int d0 = 2 * (k & 1) + 8 * (k >> 1) + 4 * hi2;
    orow[d0 >> 1]        = pkh(o0[2 * k] * inv, o0[2 * k + 1] * inv);
    orow[(d0 + 32) >> 1] = pkh(o1[2 * k] * inv, o1[2 * k + 1] * inv);
  }
  if (hi2 == 0) {
    float2* mlp = (float2*)Ml + ((size_t)(z * NH + h)) * S_LEN + q;
    *mlp = make_float2(m_q, l_q);
  }
}

// ---------------------------------------------------------------- combine
// Ab[s][1024] fp16 = weighted merge of the two normalized partials.
__global__ __launch_bounds__(256) void combine_kernel(
    const unsigned short* __restrict__ Opart, const float* __restrict__ Ml,
    unsigned short* __restrict__ Ab)
{
  const int NQ = S_LEN * 1024 / 4;
  for (int idx = blockIdx.x * 256 + threadIdx.x; idx < NQ;
       idx += gridDim.x * 256) {
    int e = idx * 4;
    int s = e >> 10;
    int col = e & 1023;
    int h = col >> 6, d = col & 63;
    const float2* mlb = (const float2*)Ml;
    float2 ml0 = mlb[(size_t)h * S_LEN + s];
    float2 ml1 = mlb[(size_t)(NH + h) * S_LEN + s];
    float mmax = fmaxf(ml0.x, ml1.x);
    float w0 = exp2f(ml0.x - mmax) * ml0.y;
    float w1 = exp2f(ml1.x - mmax) * ml1.y;
    float rden = 1.0f / (w0 + w1);
    float c0 = w0 * rden, c1 = w1 * rden;
    const unsigned short* p0 = Opart + ((size_t)h * S_LEN + s) * HD + d;
    const unsigned short* p1 = Opart + ((size_t)(NH + h) * S_LEN + s) * HD + d;
    u16x4 a = *(const u16x4*)p0;
    u16x4 b = *(const u16x4*)p1;
    u16x4 r;
#pragma unroll
    for (int j = 0; j < 4; j++)
      r[j] = f2h(c0 * h2f(a[j]) + c1 * h2f(b[j]));
    *(u16x4*)(Ab + e) = r;
  }
}

// ---------------------------------------------------------------- launch
extern "C" void kernel_launch(void* const* d_in, const int* in_sizes, int n_in,
                              void* d_out, int out_size, void* d_ws, size_t ws_size,
                              hipStream_t stream)
{
  const float* hs = (const float*)d_in[0];
  const float* Wq = (const float*)d_in[1];
  const float* Wk = (const float*)d_in[2];
  const float* Wv = (const float*)d_in[3];
  const float* Wo = (const float*)d_in[4];

  char* ws = (char*)d_ws;
  const size_t HS = (size_t)S_LEN * 1024;      // 4194304 elems
  const size_t WN = (size_t)1024 * 1024;
  size_t off = 0;
  unsigned short* hs16 = (unsigned short*)(ws + off); off += HS * 2;   // 8MB -> Q16
  unsigned short* wq16 = (unsigned short*)(ws + off); off += WN * 2;
  unsigned short* wk16 = (unsigned short*)(ws + off); off += WN * 2;
  unsigned short* wv16 = (unsigned short*)(ws + off); off += WN * 2;
  unsigned short* wo16 = (unsigned short*)(ws + off); off += WN * 2;
  unsigned short* Qh16 = (unsigned short*)(ws + off); off += HS * 2;   // 8MB \ -> Opart
  unsigned short* Kh16 = (unsigned short*)(ws + off); off += HS * 2;   // 8MB /  (16MB)
  char* Kt_g = ws + off; off += (size_t)NH * PLANE_BYTES;              // 8MB
  char* VT_g = ws + off; off += (size_t)NH * PLANE_BYTES;              // 8MB
  unsigned short* Ab = (unsigned short*)(ws + off); off += HS * 2;     // 8MB
  float* Ml = (float*)(ws + off); off += (size_t)2 * NH * S_LEN * 8;   // 1MB
  float* cosT = (float*)(ws + off); off += (size_t)S_LEN * 32 * 4;
  float* sinT = (float*)(ws + off); off += (size_t)S_LEN * 32 * 4;
  // aliases (regions dead by the time they're written):
  unsigned short* Q16 = hs16;              // hs16 dead after QKV gemm
  unsigned short* Opart = Qh16;            // Qh16+Kh16 dead after rope_apply

  cvt_kernel<<<4096, 256, 0, stream>>>(hs, Wq, Wk, Wv, Wo,
                                       hs16, wq16, wk16, wv16, wo16);

  double base = 10000.0 * pow((double)S_LEN / 2048.0, 64.0 / 62.0);
  rope_table<<<(S_LEN * 32 + 255) / 256, 256, 0, stream>>>(cosT, sinT, base);

  gemm_f16<<<dim3(8, 32, 3), 256, 0, stream>>>(
      hs16, wq16, wk16, wv16, Qh16, Kh16, VT_g, S_LEN, 1024, 0);

  rope_apply<<<NH * S_LEN / 4, 256, 0, stream>>>(
      Qh16, Kh16, Q16, Kt_g, cosT, sinT);

  attn_kernel<<<dim3(32, 16, 2), 256, 0, stream>>>(
      Q16, Kt_g, VT_g, Opart, Ml);

  combine_kernel<<<2048, 256, 0, stream>>>(Opart, Ml, Ab);

  gemm_f16<<<dim3(8, 32, 1), 256, 0, stream>>>(
      Ab, wo16, wo16, wo16, d_out, d_out, d_out, S_LEN, 1024, 1);
}

// Round 8
// 200.379 us; speedup vs baseline: 2.3710x; 1.0449x over previous
//
#include <hip/hip_runtime.h>
#include <cmath>
#include <cstdint>

#define S_LEN 4096
#define NH 16
#define HD 64

typedef _Float16 f16x8 __attribute__((ext_vector_type(8)));
typedef __attribute__((ext_vector_type(4))) float f32x4;
typedef __attribute__((ext_vector_type(16))) float f32x16;
typedef __attribute__((ext_vector_type(4))) unsigned short u16x4;
typedef __attribute__((ext_vector_type(4))) unsigned int u32x4;
typedef int i32x2 __attribute__((ext_vector_type(2)));
typedef __attribute__((ext_vector_type(4))) float f4;

__device__ __forceinline__ unsigned short f2h(float x) {
  union { _Float16 h; unsigned short u; } v; v.h = (_Float16)x; return v.u;
}
__device__ __forceinline__ float h2f(unsigned short u) {
  union { unsigned short u; _Float16 h; } v; v.u = u; return (float)v.h;
}
__device__ __forceinline__ float permx32(float v) {
  int idx = (((int)(threadIdx.x & 63)) ^ 32) << 2;
  return __int_as_float(__builtin_amdgcn_ds_bpermute(idx, __float_as_int(v)));
}
__device__ __forceinline__ float exp2a(float x) {
  float r; asm("v_exp_f32 %0, %1" : "=v"(r) : "v"(x)); return r;
}
// packs: low16 = f16(a), high16 = f16(b), round-toward-zero
__device__ __forceinline__ unsigned pkh(float a, float b) {
  unsigned r;
  asm("v_cvt_pkrtz_f16_f32 %0, %1, %2" : "=v"(r) : "v"(a), "v"(b));
  return r;
}
__device__ __forceinline__ float max3a(float a, float b, float c) {
  float r;
  asm("v_max3_f32 %0, %1, %2, %3" : "=v"(r) : "v"(a), "v"(b), "v"(c));
  return r;
}

#define GLL16(g, l) __builtin_amdgcn_global_load_lds( \
    (const __attribute__((address_space(1))) void*)(g), \
    (__attribute__((address_space(3))) void*)(l), 16, 0, 0)

// per-head byte size of a swizzled-tile plane: 4096 rows * 128B
#define PLANE_BYTES 524288
// one 64x64 2-byte tile: 8KB
#define TILE_BYTES 8192

// ---------------------------------------------------------------- convert + rope table
// blocks [0, 4096): fp32 -> fp16 conversion of all five inputs
// blocks [4096, 4608): rope cos/sin table (f64-accurate phase)
__global__ __launch_bounds__(256) void cvt_table_kernel(
    const float* __restrict__ hs, const float* __restrict__ wq,
    const float* __restrict__ wk, const float* __restrict__ wv,
    const float* __restrict__ wo,
    unsigned short* __restrict__ hs16,
    unsigned short* __restrict__ wq16, unsigned short* __restrict__ wk16,
    unsigned short* __restrict__ wv16, unsigned short* __restrict__ wo16,
    float* __restrict__ cosT, float* __restrict__ sinT, double base)
{
  if (blockIdx.x >= 4096) {
    int idx = (blockIdx.x - 4096) * 256 + threadIdx.x;
    if (idx < S_LEN * 32) {
      int t = idx >> 5, j = idx & 31;
      double invf = pow(base, -(double)j / 32.0);
      double f = fmod((double)t * invf, 6.283185307179586476925286766559);
      float ff = (float)f;
      cosT[idx] = cosf(ff);
      sinT[idx] = sinf(ff);
    }
    return;
  }
  const int HID4 = (S_LEN * 1024) / 4;
  const int W4   = (1024 * 1024) / 4;
  const int total = HID4 + 4 * W4;
  for (int i = blockIdx.x * 256 + threadIdx.x; i < total; i += 4096 * 256) {
    const float* s; unsigned short* d; int off;
    if (i < HID4) { s = hs; d = hs16; off = i; }
    else {
      int j = i - HID4; int w = j >> 18; off = j & (W4 - 1);
      s = (w == 0) ? wq : (w == 1) ? wk : (w == 2) ? wv : wo;
      d = (w == 0) ? wq16 : (w == 1) ? wk16 : (w == 2) ? wv16 : wo16;
    }
    f4 v = *(const f4*)(s + (size_t)off * 4);
    u16x4 r;
#pragma unroll
    for (int j = 0; j < 4; j++) r[j] = f2h(v[j]);
    *(u16x4*)(d + (size_t)off * 4) = r;
  }
}

// ---------------------------------------------------------------- fp16 GEMM (NT)
// C[M][N] = sum_k A[M][K]*B[N][K]; A,B fp16 row-major.
// fin=0 (QKV): z=0/1 -> fp16 [head][s][d] (Q/K); z=2 -> fp16 V^T swizzled plane.
// fin=1: fp32 out row-major [M][1024].
__global__ __launch_bounds__(256) void gemm_f16(
    const unsigned short* __restrict__ A,
    const unsigned short* __restrict__ B0, const unsigned short* __restrict__ B1,
    const unsigned short* __restrict__ B2,
    void* O0, void* O1, void* O2, int M, int K, int fin)
{
  __shared__ unsigned short As[128 * 64];
  __shared__ unsigned short Bs[128 * 64];
  const int z = blockIdx.z;
  const unsigned short* B = (z == 0) ? B0 : (z == 1) ? B1 : B2;
  void* O = (z == 0) ? O0 : (z == 1) ? O1 : O2;
  const int m0 = blockIdx.y * 128, n0 = blockIdx.x * 128;
  const int tid = threadIdx.x, wid = tid >> 6, lane = tid & 63;
  const int lr = lane & 15, lk = (lane >> 4) * 8;
  const int wr = (wid >> 1) * 64, wc = (wid & 1) * 64;
  const int strow = lane >> 3;
  const int stcol = (lane & 7) * 8;

  f32x4 acc[4][4];
#pragma unroll
  for (int m = 0; m < 4; m++)
#pragma unroll
    for (int n = 0; n < 4; n++) acc[m][n] = (f32x4){0.f, 0.f, 0.f, 0.f};

  for (int kt = 0; kt < K; kt += 64) {
#pragma unroll
    for (int i = 0; i < 4; i++) {
      int c = wid * 4 + i;
      int row = c * 8 + strow;
      GLL16(A + (size_t)(m0 + row) * K + kt + stcol, &As[c * 512]);
      GLL16(B + (size_t)(n0 + row) * K + kt + stcol, &Bs[c * 512]);
    }
    __syncthreads();
    f16x8 af[4][2], bfr[4][2];
#pragma unroll
    for (int m = 0; m < 4; m++)
#pragma unroll
      for (int kk = 0; kk < 2; kk++)
        af[m][kk] = *(const f16x8*)&As[(wr + m * 16 + lr) * 64 + kk * 32 + lk];
#pragma unroll
    for (int n = 0; n < 4; n++)
#pragma unroll
      for (int kk = 0; kk < 2; kk++)
        bfr[n][kk] = *(const f16x8*)&Bs[(wc + n * 16 + lr) * 64 + kk * 32 + lk];
#pragma unroll
    for (int m = 0; m < 4; m++)
#pragma unroll
      for (int n = 0; n < 4; n++)
#pragma unroll
        for (int kk = 0; kk < 2; kk++)
          acc[m][n] = __builtin_amdgcn_mfma_f32_16x16x32_f16(
              af[m][kk], bfr[n][kk], acc[m][n], 0, 0, 0);
    __syncthreads();
  }

  const int rbase = m0 + wr + (lane >> 4) * 4;
  const int cbase = n0 + wc + lr;
  if (fin) {
    float* C = (float*)O;
#pragma unroll
    for (int m = 0; m < 4; m++)
#pragma unroll
      for (int n = 0; n < 4; n++)
#pragma unroll
        for (int j = 0; j < 4; j++) {
          int s = rbase + m * 16 + j;
          int o = cbase + n * 16;
          C[(size_t)s * 1024 + o] = acc[m][n][j];
        }
  } else if (z == 2) {
    // V^T swizzled plane, fp16
    char* base = (char*)O;
#pragma unroll
    for (int m = 0; m < 4; m++)
#pragma unroll
      for (int n = 0; n < 4; n++) {
        int s = rbase + m * 16;            // s..s+3, s % 4 == 0
        int o = cbase + n * 16;
        int hd = o >> 6, d = o & 63;
        size_t tb = (size_t)hd * PLANE_BYTES + (size_t)(s >> 6) * TILE_BYTES
                  + (size_t)d * 128;
        int cbyte = (2 * (s & 63)) ^ ((d & 7) << 4);
        u16x4 r;
#pragma unroll
        for (int j = 0; j < 4; j++) r[j] = f2h(acc[m][n][j]);
        *(u16x4*)(base + tb + cbyte) = r;
      }
  } else {
    // Q/K: fp16 [head][s][d]
    unsigned short* C = (unsigned short*)O;
#pragma unroll
    for (int m = 0; m < 4; m++)
#pragma unroll
      for (int n = 0; n < 4; n++)
#pragma unroll
        for (int j = 0; j < 4; j++) {
          int s = rbase + m * 16 + j;
          int o = cbase + n * 16;
          C[((size_t)(o >> 6) * M + s) * HD + (o & 63)] = f2h(acc[m][n][j]);
        }
  }
}

// ---------------------------------------------------------------- rope apply
// Qh/Kh fp16 [head][s][d] -> Q16 fp16 (pre-scaled 8*log2e) + Kt swizzled plane.
__global__ __launch_bounds__(256) void rope_apply(
    const unsigned short* __restrict__ Qh, const unsigned short* __restrict__ Kh,
    unsigned short* __restrict__ Q16, char* __restrict__ Kt,
    const float* __restrict__ cosT, const float* __restrict__ sinT)
{
  int wid = threadIdx.x >> 6, lane = threadIdx.x & 63;
  int row = blockIdx.x * 4 + wid;          // 0 .. NH*S_LEN-1, [head][s]
  int t = row & (S_LEN - 1);
  int head = row >> 12;
  int j = (lane < 32) ? lane : (lane - 32);
  float c = cosT[t * 32 + j], s = sinT[t * 32 + j];
  int partner = (lane < 32) ? (2 * lane + 1) : (2 * (lane - 32));
  float sgn = (lane < 32) ? -1.0f : 1.0f;
  float q = h2f(Qh[(size_t)row * HD + lane]);
  float k = h2f(Kh[(size_t)row * HD + lane]);
  float qo = __shfl(q, partner, 64);
  float ko = __shfl(k, partner, 64);
  // fold score scale 8 and log2(e) into Q: softmax in exp2 domain
  float qr = (q * c + sgn * qo * s) * 11.541560327111707f;
  float kr = k * c + sgn * ko * s;
  Q16[(size_t)row * HD + lane] = f2h(qr);
  size_t kb = (size_t)head * PLANE_BYTES + (size_t)(t >> 6) * TILE_BYTES
            + (size_t)(t & 63) * 128 + ((2 * lane) ^ ((t & 7) << 4));
  *(unsigned short*)(Kt + kb) = f2h(kr);
}

// ---------------------------------------------------------------- attention
// Swapped-operand flash attention, fp16 32x32 MFMA, exp2-domain softmax,
// KV-split 2, software-pipelined: softmax(t) -> QK(t+1) -> PV(t).
// grid (32, 16, 2); 4 waves/block; each wave owns 32 q rows (q = qw + lane&31).
// Outputs: Opart[z][h][s][d] fp16 (normalized partial), Ml[z][h][s]=(m,l) f32.
__global__ __launch_bounds__(256, 4) void attn_kernel(
    const unsigned short* __restrict__ Q16, const char* __restrict__ Kt,
    const char* __restrict__ Vt,
    unsigned short* __restrict__ Opart, float* __restrict__ Ml)
{
  __shared__ char KL[2][TILE_BYTES];
  __shared__ char VL[2][TILE_BYTES];

  const int tid = threadIdx.x, wid = tid >> 6, lane = tid & 63;
  const int l5 = lane & 31, hi2 = lane >> 5;
  const int z = blockIdx.z;

  // head->XCD swizzle: heads {x, x+8} live on XCD x
  int id = blockIdx.x + 32 * blockIdx.y;
  int h  = (id & 7) + 8 * ((id >> 3) & 1);
  int bx = id >> 4;
  const int qw = bx * 128 + wid * 32;

  const size_t hoff = (size_t)h * PLANE_BYTES;
  const char* KtH = Kt + hoff;
  const char* VtH = Vt + hoff;

  // Q fragments: B-operand, col = q = qw + l5, k-octet d = 16ks + 8hi2 + i
  const unsigned short* Qrow = Q16 + ((size_t)h * S_LEN + qw + l5) * HD;
  f16x8 qf[4];
#pragma unroll
  for (int ks = 0; ks < 4; ks++)
    qf[ks] = *(const f16x8*)&Qrow[ks * 16 + hi2 * 8];

  f32x16 o0 = (f32x16)0.0f, o1 = (f32x16)0.0f;
  float m_q = -__builtin_inff(), l_q = 0.f;

  const int T0 = z * 32;            // first tile of this split
  const int NT = 32;                // tiles per split

#define STAGE(kt, b) do { \
    size_t tb = (size_t)(T0 + (kt)) * TILE_BYTES; \
    _Pragma("unroll") \
    for (int c = 0; c < 2; c++) { \
      int ub = c * 4096 + wid * 1024; \
      int go = ub + lane * 16; \
      GLL16(KtH + tb + go, &KL[b][ub]); \
      GLL16(VtH + tb + go, &VL[b][ub]); \
    } } while (0)

#define QKT(b) do { \
    s0 = (f32x16)0.0f; s1 = (f32x16)0.0f; \
    __builtin_amdgcn_s_setprio(1); \
    _Pragma("unroll") \
    for (int ks = 0; ks < 4; ks++) { \
      const int coff = (32 * ks + 16 * hi2) ^ ((l5 & 7) << 4); \
      f16x8 k0 = *(const f16x8*)(&KL[b][l5 * 128 + coff]); \
      f16x8 k1 = *(const f16x8*)(&KL[b][(32 + l5) * 128 + coff]); \
      s0 = __builtin_amdgcn_mfma_f32_32x32x16_f16(k0, qf[ks], s0, 0, 0, 0); \
      s1 = __builtin_amdgcn_mfma_f32_32x32x16_f16(k1, qf[ks], s1, 0, 0, 0); \
    } \
    __builtin_amdgcn_s_setprio(0); \
  } while (0)

  STAGE(0, 0);
  asm volatile("s_waitcnt vmcnt(0)" ::: "memory");
  __builtin_amdgcn_s_barrier();            // buf0 ready
  asm volatile("" ::: "memory");
  STAGE(1, 1);                             // prefetch tile 1 (fresh buffer)

  f32x16 s0, s1;
  QKT(0);                                  // scores for tile 0

  for (int kt = 0; kt < NT; ++kt) {
    const int cur = kt & 1;

    // ---- softmax(kt): per-lane, exp2 domain (q = qw + l5) ----
    // max over 32 values: max3 tree (depth 4)
    float t0 = max3a(s0[0],  s0[1],  s0[2]);
    float t1 = max3a(s0[3],  s0[4],  s0[5]);
    float t2 = max3a(s0[6],  s0[7],  s0[8]);
    float t3 = max3a(s0[9],  s0[10], s0[11]);
    float t4 = max3a(s0[12], s0[13], s0[14]);
    float t5 = max3a(s0[15], s1[0],  s1[1]);
    float t6 = max3a(s1[2],  s1[3],  s1[4]);
    float t7 = max3a(s1[5],  s1[6],  s1[7]);
    float t8 = max3a(s1[8],  s1[9],  s1[10]);
    float t9 = max3a(s1[11], s1[12], s1[13]);
    float ta = fmaxf(s1[14], s1[15]);
    float u0 = max3a(t0, t1, t2);
    float u1 = max3a(t3, t4, t5);
    float u2 = max3a(t6, t7, t8);
    float u3 = fmaxf(t9, ta);
    float mx = fmaxf(max3a(u0, u1, u2), u3);
    mx = fmaxf(mx, permx32(mx));

    // defer-max: only rescale when some lane's max grew past threshold
    if (__any(mx > m_q + 11.0f)) {
      float mnew = fmaxf(m_q, mx);
      float alpha = exp2a(m_q - mnew);
      m_q = mnew;
      l_q *= alpha;
#pragma unroll
      for (int i = 0; i < 16; i++) { o0[i] *= alpha; o1[i] *= alpha; }
    }

    // ---- P = 2^(S-m): exp/sum/pack; halves exchanged via permlane32_swap ----
    f16x8 pf[4];
    float g[4];
#pragma unroll
    for (int ks = 0; ks < 4; ks++) {
      f32x16 sv = (ks < 2) ? s0 : s1;
      const int base = (ks & 1) * 8;
      float e0 = exp2a(sv[base + 0] - m_q);
      float e1 = exp2a(sv[base + 1] - m_q);
      float e2 = exp2a(sv[base + 2] - m_q);
      float e3 = exp2a(sv[base + 3] - m_q);
      float e4 = exp2a(sv[base + 4] - m_q);
      float e5 = exp2a(sv[base + 5] - m_q);
      float e6 = exp2a(sv[base + 6] - m_q);
      float e7 = exp2a(sv[base + 7] - m_q);
      g[ks] = ((e0 + e1) + (e2 + e3)) + ((e4 + e5) + (e6 + e7));
      unsigned a0 = pkh(e0, e1);
      unsigned a1 = pkh(e2, e3);
      unsigned b0 = pkh(e4, e5);
      unsigned b1 = pkh(e6, e7);
      // swap(a,b): r[0] = {a[lanes<32] | b-from-partner for lanes>=32}
      //            r[1] = {a-from-partner for lanes<32 | b[lanes>=32]}
      // == bit-identical to the verified bpermute+select exchange.
      i32x2 r0 = __builtin_amdgcn_permlane32_swap((int)a0, (int)b0, false, false);
      i32x2 r1 = __builtin_amdgcn_permlane32_swap((int)a1, (int)b1, false, false);
      u32x4 w;
      w[0] = (unsigned)r0[0];
      w[1] = (unsigned)r1[0];
      w[2] = (unsigned)r0[1];
      w[3] = (unsigned)r1[1];
      union { u32x4 u; f16x8 f; } cv; cv.u = w;
      pf[ks] = cv.f;
    }
    float rs = (g[0] + g[1]) + (g[2] + g[3]);
    rs += permx32(rs);
    l_q += rs;

    // ---- QK(kt+1): scores for next tile (overwrites s0,s1; pf(kt) held) ----
    if (kt + 1 < NT) {
      asm volatile("s_waitcnt vmcnt(0)" ::: "memory");   // drain STAGE(kt+1)
      __builtin_amdgcn_s_barrier();                      // buf[cur^1] ready
      asm volatile("" ::: "memory");
      QKT(cur ^ 1);
    }

    // ---- PV(kt): O^T += V^T P from buf[cur] ----
    __builtin_amdgcn_s_setprio(1);
#pragma unroll
    for (int ks = 0; ks < 4; ks++) {
      const int coff = (32 * ks + 16 * hi2) ^ ((l5 & 7) << 4);
      f16x8 v0 = *(const f16x8*)(&VL[cur][l5 * 128 + coff]);
      f16x8 v1 = *(const f16x8*)(&VL[cur][(32 + l5) * 128 + coff]);
      o0 = __builtin_amdgcn_mfma_f32_32x32x16_f16(v0, pf[ks], o0, 0, 0, 0);
      o1 = __builtin_amdgcn_mfma_f32_32x32x16_f16(v1, pf[ks], o1, 0, 0, 0);
    }
    __builtin_amdgcn_s_setprio(0);

    asm volatile("" ::: "memory");
    __builtin_amdgcn_s_barrier();                        // buf[cur] free
    asm volatile("" ::: "memory");
    if (kt + 2 < NT) STAGE(kt + 2, cur);                 // refill buf[cur]
  }
#undef STAGE
#undef QKT

  // ---- epilogue: normalized partial fp16 + (m,l) ----
  const float inv = 1.0f / l_q;
  const int q = qw + l5;
  unsigned* orow = (unsigned*)(Opart + (((size_t)(z * NH + h)) * S_LEN + q) * HD);
#pragma unroll
  for (int k = 0; k < 8; k++) {
    const int d0 = 2 * (k & 1) + 8 * (k >> 1) + 4 * hi2;
    orow[d0 >> 1]        = pkh(o0[2 * k] * inv, o0[2 * k + 1] * inv);
    orow[(d0 + 32) >> 1] = pkh(o1[2 * k] * inv, o1[2 * k + 1] * inv);
  }
  if (hi2 == 0) {
    float2* mlp = (float2*)Ml + ((size_t)(z * NH + h)) * S_LEN + q;
    *mlp = make_float2(m_q, l_q);
  }
}

// ---------------------------------------------------------------- combine
// Ab[s][1024] fp16 = weighted merge of the two normalized partials.
__global__ __launch_bounds__(256) void combine_kernel(
    const unsigned short* __restrict__ Opart, const float* __restrict__ Ml,
    unsigned short* __restrict__ Ab)
{
  const int NQ = S_LEN * 1024 / 4;
  for (int idx = blockIdx.x * 256 + threadIdx.x; idx < NQ;
       idx += gridDim.x * 256) {
    int e = idx * 4;
    int s = e >> 10;
    int col = e & 1023;
    int h = col >> 6, d = col & 63;
    const float2* mlb = (const float2*)Ml;
    float2 ml0 = mlb[(size_t)h * S_LEN + s];
    float2 ml1 = mlb[(size_t)(NH + h) * S_LEN + s];
    float mmax = fmaxf(ml0.x, ml1.x);
    float w0 = exp2f(ml0.x - mmax) * ml0.y;
    float w1 = exp2f(ml1.x - mmax) * ml1.y;
    float rden = 1.0f / (w0 + w1);
    float c0 = w0 * rden, c1 = w1 * rden;
    const unsigned short* p0 = Opart + ((size_t)h * S_LEN + s) * HD + d;
    const unsigned short* p1 = Opart + ((size_t)(NH + h) * S_LEN + s) * HD + d;
    u16x4 a = *(const u16x4*)p0;
    u16x4 b = *(const u16x4*)p1;
    u16x4 r;
#pragma unroll
    for (int j = 0; j < 4; j++)
      r[j] = f2h(c0 * h2f(a[j]) + c1 * h2f(b[j]));
    *(u16x4*)(Ab + e) = r;
  }
}

// ---------------------------------------------------------------- launch
extern "C" void kernel_launch(void* const* d_in, const int* in_sizes, int n_in,
                              void* d_out, int out_size, void* d_ws, size_t ws_size,
                              hipStream_t stream)
{
  const float* hs = (const float*)d_in[0];
  const float* Wq = (const float*)d_in[1];
  const float* Wk = (const float*)d_in[2];
  const float* Wv = (const float*)d_in[3];
  const float* Wo = (const float*)d_in[4];

  char* ws = (char*)d_ws;
  const size_t HS = (size_t)S_LEN * 1024;      // 4194304 elems
  const size_t WN = (size_t)1024 * 1024;
  size_t off = 0;
  unsigned short* hs16 = (unsigned short*)(ws + off); off += HS * 2;   // 8MB -> Q16
  unsigned short* wq16 = (unsigned short*)(ws + off); off += WN * 2;
  unsigned short* wk16 = (unsigned short*)(ws + off); off += WN * 2;
  unsigned short* wv16 = (unsigned short*)(ws + off); off += WN * 2;
  unsigned short* wo16 = (unsigned short*)(ws + off); off += WN * 2;
  unsigned short* Qh16 = (unsigned short*)(ws + off); off += HS * 2;   // 8MB \ -> Opart
  unsigned short* Kh16 = (unsigned short*)(ws + off); off += HS * 2;   // 8MB /  (16MB)
  char* Kt_g = ws + off; off += (size_t)NH * PLANE_BYTES;              // 8MB
  char* VT_g = ws + off; off += (size_t)NH * PLANE_BYTES;              // 8MB
  unsigned short* Ab = (unsigned short*)(ws + off); off += HS * 2;     // 8MB
  float* Ml = (float*)(ws + off); off += (size_t)2 * NH * S_LEN * 8;   // 1MB
  float* cosT = (float*)(ws + off); off += (size_t)S_LEN * 32 * 4;
  float* sinT = (float*)(ws + off); off += (size_t)S_LEN * 32 * 4;
  // aliases (regions dead by the time they're written):
  unsigned short* Q16 = hs16;              // hs16 dead after QKV gemm
  unsigned short* Opart = Qh16;            // Qh16+Kh16 dead after rope_apply

  double base = 10000.0 * pow((double)S_LEN / 2048.0, 64.0 / 62.0);

  cvt_table_kernel<<<4608, 256, 0, stream>>>(hs, Wq, Wk, Wv, Wo,
                                             hs16, wq16, wk16, wv16, wo16,
                                             cosT, sinT, base);

  gemm_f16<<<dim3(8, 32, 3), 256, 0, stream>>>(
      hs16, wq16, wk16, wv16, Qh16, Kh16, VT_g, S_LEN, 1024, 0);

  rope_apply<<<NH * S_LEN / 4, 256, 0, stream>>>(
      Qh16, Kh16, Q16, Kt_g, cosT, sinT);

  attn_kernel<<<dim3(32, 16, 2), 256, 0, stream>>>(
      Q16, Kt_g, VT_g, Opart, Ml);

  combine_kernel<<<2048, 256, 0, stream>>>(Opart, Ml, Ab);

  gemm_f16<<<dim3(8, 32, 1), 256, 0, stream>>>(
      Ab, wo16, wo16, wo16, d_out, d_out, d_out, S_LEN, 1024, 1);
}

// Round 9
// 195.485 us; speedup vs baseline: 2.4304x; 1.0250x over previous
//
#include <hip/hip_runtime.h>
#include <cmath>
#include <cstdint>

#define S_LEN 4096
#define NH 16
#define HD 64

typedef _Float16 f16x8 __attribute__((ext_vector_type(8)));
typedef __attribute__((ext_vector_type(4))) float f32x4;
typedef __attribute__((ext_vector_type(16))) float f32x16;
typedef __attribute__((ext_vector_type(4))) unsigned short u16x4;
typedef __attribute__((ext_vector_type(4))) unsigned int u32x4;
typedef int i32x2 __attribute__((ext_vector_type(2)));
typedef __attribute__((ext_vector_type(4))) float f4;

__device__ __forceinline__ unsigned short f2h(float x) {
  union { _Float16 h; unsigned short u; } v; v.h = (_Float16)x; return v.u;
}
__device__ __forceinline__ float h2f(unsigned short u) {
  union { unsigned short u; _Float16 h; } v; v.u = u; return (float)v.h;
}
__device__ __forceinline__ float exp2a(float x) {
  float r; asm("v_exp_f32 %0, %1" : "=v"(r) : "v"(x)); return r;
}
// packs: low16 = f16(a), high16 = f16(b), round-toward-zero
__device__ __forceinline__ unsigned pkh(float a, float b) {
  unsigned r;
  asm("v_cvt_pkrtz_f16_f32 %0, %1, %2" : "=v"(r) : "v"(a), "v"(b));
  return r;
}
__device__ __forceinline__ float max3a(float a, float b, float c) {
  float r;
  asm("v_max3_f32 %0, %1, %2, %3" : "=v"(r) : "v"(a), "v"(b), "v"(c));
  return r;
}
// cross-half partner value via permlane32_swap (no LDS pipe):
// partner(lane) = lane ^ 32.  first[i<32]=v[i], first[i>=32]=v[i-32];
// second[i<32]=v[i+32], second[i>=32]=v[i]  => partner = hi ? first : second.
__device__ __forceinline__ float swapx32(float v, int hi2) {
  i32x2 r = __builtin_amdgcn_permlane32_swap(__float_as_int(v), __float_as_int(v),
                                             false, false);
  return __int_as_float(hi2 ? r[0] : r[1]);
}

#define GLL16(g, l) __builtin_amdgcn_global_load_lds( \
    (const __attribute__((address_space(1))) void*)(g), \
    (__attribute__((address_space(3))) void*)(l), 16, 0, 0)

// per-head byte size of a swizzled-tile plane: 4096 rows * 128B
#define PLANE_BYTES 524288
// one 64x64 2-byte tile: 8KB
#define TILE_BYTES 8192

// ---------------------------------------------------------------- convert + rope table
// blocks [0, 4096): fp32 -> fp16 conversion of all five inputs
// blocks [4096, 4608): rope cos/sin table (f64-accurate phase)
__global__ __launch_bounds__(256) void cvt_table_kernel(
    const float* __restrict__ hs, const float* __restrict__ wq,
    const float* __restrict__ wk, const float* __restrict__ wv,
    const float* __restrict__ wo,
    unsigned short* __restrict__ hs16,
    unsigned short* __restrict__ wq16, unsigned short* __restrict__ wk16,
    unsigned short* __restrict__ wv16, unsigned short* __restrict__ wo16,
    float* __restrict__ cosT, float* __restrict__ sinT, double base)
{
  if (blockIdx.x >= 4096) {
    int idx = (blockIdx.x - 4096) * 256 + threadIdx.x;
    if (idx < S_LEN * 32) {
      int t = idx >> 5, j = idx & 31;
      double invf = pow(base, -(double)j / 32.0);
      double f = fmod((double)t * invf, 6.283185307179586476925286766559);
      float ff = (float)f;
      cosT[idx] = cosf(ff);
      sinT[idx] = sinf(ff);
    }
    return;
  }
  const int HID4 = (S_LEN * 1024) / 4;
  const int W4   = (1024 * 1024) / 4;
  const int total = HID4 + 4 * W4;
  for (int i = blockIdx.x * 256 + threadIdx.x; i < total; i += 4096 * 256) {
    const float* s; unsigned short* d; int off;
    if (i < HID4) { s = hs; d = hs16; off = i; }
    else {
      int j = i - HID4; int w = j >> 18; off = j & (W4 - 1);
      s = (w == 0) ? wq : (w == 1) ? wk : (w == 2) ? wv : wo;
      d = (w == 0) ? wq16 : (w == 1) ? wk16 : (w == 2) ? wv16 : wo16;
    }
    f4 v = *(const f4*)(s + (size_t)off * 4);
    u16x4 r;
#pragma unroll
    for (int j = 0; j < 4; j++) r[j] = f2h(v[j]);
    *(u16x4*)(d + (size_t)off * 4) = r;
  }
}

// ---------------------------------------------------------------- fp16 GEMM (NT)
// C[M][N] = sum_k A[M][K]*B[N][K]; A,B fp16 row-major.
// fin=0 (QKV): z=0/1 -> fp16 [head][s][d] (Q/K); z=2 -> fp16 V^T swizzled plane.
// fin=1: fp32 out row-major [M][1024].
__global__ __launch_bounds__(256) void gemm_f16(
    const unsigned short* __restrict__ A,
    const unsigned short* __restrict__ B0, const unsigned short* __restrict__ B1,
    const unsigned short* __restrict__ B2,
    void* O0, void* O1, void* O2, int M, int K, int fin)
{
  __shared__ unsigned short As[128 * 64];
  __shared__ unsigned short Bs[128 * 64];
  const int z = blockIdx.z;
  const unsigned short* B = (z == 0) ? B0 : (z == 1) ? B1 : B2;
  void* O = (z == 0) ? O0 : (z == 1) ? O1 : O2;
  const int m0 = blockIdx.y * 128, n0 = blockIdx.x * 128;
  const int tid = threadIdx.x, wid = tid >> 6, lane = tid & 63;
  const int lr = lane & 15, lk = (lane >> 4) * 8;
  const int wr = (wid >> 1) * 64, wc = (wid & 1) * 64;
  const int strow = lane >> 3;
  const int stcol = (lane & 7) * 8;

  f32x4 acc[4][4];
#pragma unroll
  for (int m = 0; m < 4; m++)
#pragma unroll
    for (int n = 0; n < 4; n++) acc[m][n] = (f32x4){0.f, 0.f, 0.f, 0.f};

  for (int kt = 0; kt < K; kt += 64) {
#pragma unroll
    for (int i = 0; i < 4; i++) {
      int c = wid * 4 + i;
      int row = c * 8 + strow;
      GLL16(A + (size_t)(m0 + row) * K + kt + stcol, &As[c * 512]);
      GLL16(B + (size_t)(n0 + row) * K + kt + stcol, &Bs[c * 512]);
    }
    __syncthreads();
    f16x8 af[4][2], bfr[4][2];
#pragma unroll
    for (int m = 0; m < 4; m++)
#pragma unroll
      for (int kk = 0; kk < 2; kk++)
        af[m][kk] = *(const f16x8*)&As[(wr + m * 16 + lr) * 64 + kk * 32 + lk];
#pragma unroll
    for (int n = 0; n < 4; n++)
#pragma unroll
      for (int kk = 0; kk < 2; kk++)
        bfr[n][kk] = *(const f16x8*)&Bs[(wc + n * 16 + lr) * 64 + kk * 32 + lk];
#pragma unroll
    for (int m = 0; m < 4; m++)
#pragma unroll
      for (int n = 0; n < 4; n++)
#pragma unroll
        for (int kk = 0; kk < 2; kk++)
          acc[m][n] = __builtin_amdgcn_mfma_f32_16x16x32_f16(
              af[m][kk], bfr[n][kk], acc[m][n], 0, 0, 0);
    __syncthreads();
  }

  const int rbase = m0 + wr + (lane >> 4) * 4;
  const int cbase = n0 + wc + lr;
  if (fin) {
    float* C = (float*)O;
#pragma unroll
    for (int m = 0; m < 4; m++)
#pragma unroll
      for (int n = 0; n < 4; n++)
#pragma unroll
        for (int j = 0; j < 4; j++) {
          int s = rbase + m * 16 + j;
          int o = cbase + n * 16;
          C[(size_t)s * 1024 + o] = acc[m][n][j];
        }
  } else if (z == 2) {
    // V^T swizzled plane, fp16
    char* base = (char*)O;
#pragma unroll
    for (int m = 0; m < 4; m++)
#pragma unroll
      for (int n = 0; n < 4; n++) {
        int s = rbase + m * 16;            // s..s+3, s % 4 == 0
        int o = cbase + n * 16;
        int hd = o >> 6, d = o & 63;
        size_t tb = (size_t)hd * PLANE_BYTES + (size_t)(s >> 6) * TILE_BYTES
                  + (size_t)d * 128;
        int cbyte = (2 * (s & 63)) ^ ((d & 7) << 4);
        u16x4 r;
#pragma unroll
        for (int j = 0; j < 4; j++) r[j] = f2h(acc[m][n][j]);
        *(u16x4*)(base + tb + cbyte) = r;
      }
  } else {
    // Q/K: fp16 [head][s][d]
    unsigned short* C = (unsigned short*)O;
#pragma unroll
    for (int m = 0; m < 4; m++)
#pragma unroll
      for (int n = 0; n < 4; n++)
#pragma unroll
        for (int j = 0; j < 4; j++) {
          int s = rbase + m * 16 + j;
          int o = cbase + n * 16;
          C[((size_t)(o >> 6) * M + s) * HD + (o & 63)] = f2h(acc[m][n][j]);
        }
  }
}

// ---------------------------------------------------------------- rope apply
// Qh/Kh fp16 [head][s][d] -> Q16 fp16 (pre-scaled 8*log2e) + Kt swizzled plane.
__global__ __launch_bounds__(256) void rope_apply(
    const unsigned short* __restrict__ Qh, const unsigned short* __restrict__ Kh,
    unsigned short* __restrict__ Q16, char* __restrict__ Kt,
    const float* __restrict__ cosT, const float* __restrict__ sinT)
{
  int wid = threadIdx.x >> 6, lane = threadIdx.x & 63;
  int row = blockIdx.x * 4 + wid;          // 0 .. NH*S_LEN-1, [head][s]
  int t = row & (S_LEN - 1);
  int head = row >> 12;
  int j = (lane < 32) ? lane : (lane - 32);
  float c = cosT[t * 32 + j], s = sinT[t * 32 + j];
  int partner = (lane < 32) ? (2 * lane + 1) : (2 * (lane - 32));
  float sgn = (lane < 32) ? -1.0f : 1.0f;
  float q = h2f(Qh[(size_t)row * HD + lane]);
  float k = h2f(Kh[(size_t)row * HD + lane]);
  float qo = __shfl(q, partner, 64);
  float ko = __shfl(k, partner, 64);
  // fold score scale 8 and log2(e) into Q: softmax in exp2 domain
  float qr = (q * c + sgn * qo * s) * 11.541560327111707f;
  float kr = k * c + sgn * ko * s;
  Q16[(size_t)row * HD + lane] = f2h(qr);
  size_t kb = (size_t)head * PLANE_BYTES + (size_t)(t >> 6) * TILE_BYTES
            + (size_t)(t & 63) * 128 + ((2 * lane) ^ ((t & 7) << 4));
  *(unsigned short*)(Kt + kb) = f2h(kr);
}

// ---------------------------------------------------------------- attention
// Swapped-operand flash attention, fp16 32x32 MFMA, exp2-domain softmax,
// KV-split 2, pipelined: SM(t)+PV(t) interleaved -> QK(t+1) -> STAGE(t+2).
// grid (32, 16, 2); 4 waves/block; each wave owns 32 q rows (q = qw + lane&31).
// Outputs: Opart[z][h][s][d] fp16 (normalized partial), Ml[z][h][s]=(m,l) f32.
__global__ __launch_bounds__(256, 4) void attn_kernel(
    const unsigned short* __restrict__ Q16, const char* __restrict__ Kt,
    const char* __restrict__ Vt,
    unsigned short* __restrict__ Opart, float* __restrict__ Ml)
{
  __shared__ char KL[2][TILE_BYTES];
  __shared__ char VL[2][TILE_BYTES];

  const int tid = threadIdx.x, wid = tid >> 6, lane = tid & 63;
  const int l5 = lane & 31, hi2 = lane >> 5;
  const int z = blockIdx.z;

  // head->XCD swizzle: heads {x, x+8} live on XCD x
  int id = blockIdx.x + 32 * blockIdx.y;
  int h  = (id & 7) + 8 * ((id >> 3) & 1);
  int bx = id >> 4;
  const int qw = bx * 128 + wid * 32;

  const size_t hoff = (size_t)h * PLANE_BYTES;
  const char* KtH = Kt + hoff;
  const char* VtH = Vt + hoff;

  // Q fragments: B-operand, col = q = qw + l5, k-octet d = 16ks + 8hi2 + i
  const unsigned short* Qrow = Q16 + ((size_t)h * S_LEN + qw + l5) * HD;
  f16x8 qf[4];
#pragma unroll
  for (int ks = 0; ks < 4; ks++)
    qf[ks] = *(const f16x8*)&Qrow[ks * 16 + hi2 * 8];

  f32x16 o0 = (f32x16)0.0f, o1 = (f32x16)0.0f;
  float m_q = -__builtin_inff(), l_q = 0.f;

  const int T0 = z * 32;            // first tile of this split
  const int NT = 32;                // tiles per split

#define STAGE(kt, b) do { \
    size_t tb = (size_t)(T0 + (kt)) * TILE_BYTES; \
    _Pragma("unroll") \
    for (int c = 0; c < 2; c++) { \
      int ub = c * 4096 + wid * 1024; \
      int go = ub + lane * 16; \
      GLL16(KtH + tb + go, &KL[b][ub]); \
      GLL16(VtH + tb + go, &VL[b][ub]); \
    } } while (0)

#define QKT(b) do { \
    s0 = (f32x16)0.0f; s1 = (f32x16)0.0f; \
    __builtin_amdgcn_s_setprio(1); \
    _Pragma("unroll") \
    for (int ks = 0; ks < 4; ks++) { \
      const int coff = (32 * ks + 16 * hi2) ^ ((l5 & 7) << 4); \
      f16x8 k0 = *(const f16x8*)(&KL[b][l5 * 128 + coff]); \
      f16x8 k1 = *(const f16x8*)(&KL[b][(32 + l5) * 128 + coff]); \
      s0 = __builtin_amdgcn_mfma_f32_32x32x16_f16(k0, qf[ks], s0, 0, 0, 0); \
      s1 = __builtin_amdgcn_mfma_f32_32x32x16_f16(k1, qf[ks], s1, 0, 0, 0); \
    } \
    __builtin_amdgcn_s_setprio(0); \
  } while (0)

  STAGE(0, 0);
  asm volatile("s_waitcnt vmcnt(0)" ::: "memory");
  __builtin_amdgcn_s_barrier();            // buf0 ready
  asm volatile("" ::: "memory");
  STAGE(1, 1);                             // prefetch tile 1 (fresh buffer)

  f32x16 s0, s1;
  QKT(0);                                  // scores for tile 0

  for (int kt = 0; kt < NT; ++kt) {
    const int cur = kt & 1;

    // ---- softmax-max(kt): per-lane, exp2 domain (q = qw + l5) ----
    float t0 = max3a(s0[0],  s0[1],  s0[2]);
    float t1 = max3a(s0[3],  s0[4],  s0[5]);
    float t2 = max3a(s0[6],  s0[7],  s0[8]);
    float t3 = max3a(s0[9],  s0[10], s0[11]);
    float t4 = max3a(s0[12], s0[13], s0[14]);
    float t5 = max3a(s0[15], s1[0],  s1[1]);
    float t6 = max3a(s1[2],  s1[3],  s1[4]);
    float t7 = max3a(s1[5],  s1[6],  s1[7]);
    float t8 = max3a(s1[8],  s1[9],  s1[10]);
    float t9 = max3a(s1[11], s1[12], s1[13]);
    float ta = fmaxf(s1[14], s1[15]);
    float u0 = max3a(t0, t1, t2);
    float u1 = max3a(t3, t4, t5);
    float u2 = max3a(t6, t7, t8);
    float u3 = fmaxf(t9, ta);
    float mx = fmaxf(max3a(u0, u1, u2), u3);
    mx = fmaxf(mx, swapx32(mx, hi2));

    // defer-max: only rescale when some lane's max grew past threshold
    if (__any(mx > m_q + 11.0f)) {
      float mnew = fmaxf(m_q, mx);
      float alpha = exp2a(m_q - mnew);
      m_q = mnew;
      l_q *= alpha;
#pragma unroll
      for (int i = 0; i < 16; i++) { o0[i] *= alpha; o1[i] *= alpha; }
    }

    // ---- P=2^(S-m) interleaved with PV: per ks {exp8, pack, swap, 2 MFMA} ----
    // pf is a 4-reg transient; exp (TRANS) overlaps the PV MFMAs of the
    // previous ks batch (separate pipes).
    float g0, g1, g2, g3;
#pragma unroll
    for (int ks = 0; ks < 4; ks++) {
      const int base = (ks & 1) * 8;
      float e0, e1, e2, e3, e4, e5, e6, e7;
      if (ks < 2) {
        e0 = exp2a(s0[base + 0] - m_q); e1 = exp2a(s0[base + 1] - m_q);
        e2 = exp2a(s0[base + 2] - m_q); e3 = exp2a(s0[base + 3] - m_q);
        e4 = exp2a(s0[base + 4] - m_q); e5 = exp2a(s0[base + 5] - m_q);
        e6 = exp2a(s0[base + 6] - m_q); e7 = exp2a(s0[base + 7] - m_q);
      } else {
        e0 = exp2a(s1[base + 0] - m_q); e1 = exp2a(s1[base + 1] - m_q);
        e2 = exp2a(s1[base + 2] - m_q); e3 = exp2a(s1[base + 3] - m_q);
        e4 = exp2a(s1[base + 4] - m_q); e5 = exp2a(s1[base + 5] - m_q);
        e6 = exp2a(s1[base + 6] - m_q); e7 = exp2a(s1[base + 7] - m_q);
      }
      float gs = ((e0 + e1) + (e2 + e3)) + ((e4 + e5) + (e6 + e7));
      if (ks == 0) g0 = gs; else if (ks == 1) g1 = gs;
      else if (ks == 2) g2 = gs; else g3 = gs;
      unsigned a0 = pkh(e0, e1);
      unsigned a1 = pkh(e2, e3);
      unsigned b0 = pkh(e4, e5);
      unsigned b1 = pkh(e6, e7);
      i32x2 r0 = __builtin_amdgcn_permlane32_swap((int)a0, (int)b0, false, false);
      i32x2 r1 = __builtin_amdgcn_permlane32_swap((int)a1, (int)b1, false, false);
      u32x4 w;
      w[0] = (unsigned)r0[0];
      w[1] = (unsigned)r1[0];
      w[2] = (unsigned)r0[1];
      w[3] = (unsigned)r1[1];
      union { u32x4 u; f16x8 f; } cv; cv.u = w;
      const int coff = (32 * ks + 16 * hi2) ^ ((l5 & 7) << 4);
      f16x8 v0 = *(const f16x8*)(&VL[cur][l5 * 128 + coff]);
      f16x8 v1 = *(const f16x8*)(&VL[cur][(32 + l5) * 128 + coff]);
      o0 = __builtin_amdgcn_mfma_f32_32x32x16_f16(v0, cv.f, o0, 0, 0, 0);
      o1 = __builtin_amdgcn_mfma_f32_32x32x16_f16(v1, cv.f, o1, 0, 0, 0);
    }
    float rs = (g0 + g1) + (g2 + g3);
    rs += swapx32(rs, hi2);
    l_q += rs;

    // ---- QK(kt+1): scores for next tile (pure MFMA cluster) ----
    if (kt + 1 < NT) {
      asm volatile("s_waitcnt vmcnt(0)" ::: "memory");   // drain STAGE(kt+1)
      __builtin_amdgcn_s_barrier();                      // buf[cur^1] ready
      asm volatile("" ::: "memory");
      QKT(cur ^ 1);
    }

    asm volatile("" ::: "memory");
    __builtin_amdgcn_s_barrier();                        // buf[cur] free
    asm volatile("" ::: "memory");
    if (kt + 2 < NT) STAGE(kt + 2, cur);                 // refill buf[cur]
  }
#undef STAGE
#undef QKT

  // ---- epilogue: normalized partial fp16 + (m,l) ----
  const float inv = 1.0f / l_q;
  const int q = qw + l5;
  unsigned* orow = (unsigned*)(Opart + (((size_t)(z * NH + h)) * S_LEN + q) * HD);
#pragma unroll
  for (int k = 0; k < 8; k++) {
    const int d0 = 2 * (k & 1) + 8 * (k >> 1) + 4 * hi2;
    orow[d0 >> 1]        = pkh(o0[2 * k] * inv, o0[2 * k + 1] * inv);
    orow[(d0 + 32) >> 1] = pkh(o1[2 * k] * inv, o1[2 * k + 1] * inv);
  }
  if (hi2 == 0) {
    float2* mlp = (float2*)Ml + ((size_t)(z * NH + h)) * S_LEN + q;
    *mlp = make_float2(m_q, l_q);
  }
}

// ---------------------------------------------------------------- combine
// Ab[s][1024] fp16 = weighted merge of the two normalized partials.
__global__ __launch_bounds__(256) void combine_kernel(
    const unsigned short* __restrict__ Opart, const float* __restrict__ Ml,
    unsigned short* __restrict__ Ab)
{
  const int NQ = S_LEN * 1024 / 4;
  for (int idx = blockIdx.x * 256 + threadIdx.x; idx < NQ;
       idx += gridDim.x * 256) {
    int e = idx * 4;
    int s = e >> 10;
    int col = e & 1023;
    int h = col >> 6, d = col & 63;
    const float2* mlb = (const float2*)Ml;
    float2 ml0 = mlb[(size_t)h * S_LEN + s];
    float2 ml1 = mlb[(size_t)(NH + h) * S_LEN + s];
    float mmax = fmaxf(ml0.x, ml1.x);
    float w0 = exp2f(ml0.x - mmax) * ml0.y;
    float w1 = exp2f(ml1.x - mmax) * ml1.y;
    float rden = 1.0f / (w0 + w1);
    float c0 = w0 * rden, c1 = w1 * rden;
    const unsigned short* p0 = Opart + ((size_t)h * S_LEN + s) * HD + d;
    const unsigned short* p1 = Opart + ((size_t)(NH + h) * S_LEN + s) * HD + d;
    u16x4 a = *(const u16x4*)p0;
    u16x4 b = *(const u16x4*)p1;
    u16x4 r;
#pragma unroll
    for (int j = 0; j < 4; j++)
      r[j] = f2h(c0 * h2f(a[j]) + c1 * h2f(b[j]));
    *(u16x4*)(Ab + e) = r;
  }
}

// ---------------------------------------------------------------- launch
extern "C" void kernel_launch(void* const* d_in, const int* in_sizes, int n_in,
                              void* d_out, int out_size, void* d_ws, size_t ws_size,
                              hipStream_t stream)
{
  const float* hs = (const float*)d_in[0];
  const float* Wq = (const float*)d_in[1];
  const float* Wk = (const float*)d_in[2];
  const float* Wv = (const float*)d_in[3];
  const float* Wo = (const float*)d_in[4];

  char* ws = (char*)d_ws;
  const size_t HS = (size_t)S_LEN * 1024;      // 4194304 elems
  const size_t WN = (size_t)1024 * 1024;
  size_t off = 0;
  unsigned short* hs16 = (unsigned short*)(ws + off); off += HS * 2;   // 8MB -> Q16
  unsigned short* wq16 = (unsigned short*)(ws + off); off += WN * 2;
  unsigned short* wk16 = (unsigned short*)(ws + off); off += WN * 2;
  unsigned short* wv16 = (unsigned short*)(ws + off); off += WN * 2;
  unsigned short* wo16 = (unsigned short*)(ws + off); off += WN * 2;
  unsigned short* Qh16 = (unsigned short*)(ws + off); off += HS * 2;   // 8MB \ -> Opart
  unsigned short* Kh16 = (unsigned short*)(ws + off); off += HS * 2;   // 8MB /  (16MB)
  char* Kt_g = ws + off; off += (size_t)NH * PLANE_BYTES;              // 8MB
  char* VT_g = ws + off; off += (size_t)NH * PLANE_BYTES;              // 8MB
  unsigned short* Ab = (unsigned short*)(ws + off); off += HS * 2;     // 8MB
  float* Ml = (float*)(ws + off); off += (size_t)2 * NH * S_LEN * 8;   // 1MB
  float* cosT = (float*)(ws + off); off += (size_t)S_LEN * 32 * 4;
  float* sinT = (float*)(ws + off); off += (size_t)S_LEN * 32 * 4;
  // aliases (regions dead by the time they're written):
  unsigned short* Q16 = hs16;              // hs16 dead after QKV gemm
  unsigned short* Opart = Qh16;            // Qh16+Kh16 dead after rope_apply

  double base = 10000.0 * pow((double)S_LEN / 2048.0, 64.0 / 62.0);

  cvt_table_kernel<<<4608, 256, 0, stream>>>(hs, Wq, Wk, Wv, Wo,
                                             hs16, wq16, wk16, wv16, wo16,
                                             cosT, sinT, base);

  gemm_f16<<<dim3(8, 32, 3), 256, 0, stream>>>(
      hs16, wq16, wk16, wv16, Qh16, Kh16, VT_g, S_LEN, 1024, 0);

  rope_apply<<<NH * S_LEN / 4, 256, 0, stream>>>(
      Qh16, Kh16, Q16, Kt_g, cosT, sinT);

  attn_kernel<<<dim3(32, 16, 2), 256, 0, stream>>>(
      Q16, Kt_g, VT_g, Opart, Ml);

  combine_kernel<<<2048, 256, 0, stream>>>(Opart, Ml, Ab);

  gemm_f16<<<dim3(8, 32, 1), 256, 0, stream>>>(
      Ab, wo16, wo16, wo16, d_out, d_out, d_out, S_LEN, 1024, 1);
}